// Round 3
// baseline (2211.193 us; speedup 1.0000x reference)
//
#include <hip/hip_runtime.h>
#include <cstdint>
#include <cstddef>

#define NPTS 262144
#define BLK 256
#define TGX 176
#define TGY 200
#define TGZ 1

#define SCAN_ITEMS 32
#define SCAN_CHUNK (BLK*SCAN_ITEMS)

// ---------------- voxel coord helpers ----------------
__device__ __forceinline__ void pcoords(float x, float y, float z,
    float vx, float vy, float vz, int gx, int gy, int gz,
    int& cx, int& cy, int& cz) {
  cx = (int)floorf((x - 0.0f)  / vx);
  cy = (int)floorf((y + 40.0f) / vy);
  cz = (int)floorf((z + 3.0f)  / vz);
  cx = min(max(cx, 0), gx - 1);
  cy = min(max(cy, 0), gy - 1);
  cz = min(max(cz, 0), gz - 1);
}

// ---------------- pass 1: dense count grid ----------------
__global__ __launch_bounds__(BLK) void k_count(const float* __restrict__ pts,
    int* __restrict__ cnt, int gx, int gy, int gz, float vx, float vy, float vz) {
  int i = blockIdx.x * BLK + threadIdx.x;
  if (i >= NPTS) return;
  float b = pts[i*5+0], x = pts[i*5+1], y = pts[i*5+2], z = pts[i*5+3];
  int cx, cy, cz; pcoords(x, y, z, vx, vy, vz, gx, gy, gz, cx, cy, cz);
  int lin = (((int)b * gz + cz) * gy + cy) * gx + cx;
  atomicAdd(&cnt[lin], 1);
}

// ---------------- occupancy+count scan (3 phases) ----------------
__global__ __launch_bounds__(BLK) void k_scan1(const int* __restrict__ cnt, int G,
                                               int2* __restrict__ bsum) {
  int base = blockIdx.x * SCAN_CHUNK + threadIdx.x * SCAN_ITEMS;
  int so = 0, sp = 0;
  #pragma unroll
  for (int k = 0; k < SCAN_ITEMS; k++) {
    int j = base + k;
    if (j < G) { int c = cnt[j]; if (c > 0) { so++; sp += c; } }
  }
  __shared__ int sho[BLK], shp[BLK];
  sho[threadIdx.x] = so; shp[threadIdx.x] = sp; __syncthreads();
  for (int off = BLK/2; off > 0; off >>= 1) {
    if (threadIdx.x < off) {
      sho[threadIdx.x] += sho[threadIdx.x + off];
      shp[threadIdx.x] += shp[threadIdx.x + off];
    }
    __syncthreads();
  }
  if (threadIdx.x == 0) { int2 v; v.x = sho[0]; v.y = shp[0]; bsum[blockIdx.x] = v; }
}

__global__ __launch_bounds__(1024) void k_scan2(int2* __restrict__ bsum, int nb,
                                                int* __restrict__ U) {
  __shared__ int so[1024], sp[1024];
  int t = threadIdx.x;
  int vo = 0, vp = 0;
  if (t < nb) { int2 v = bsum[t]; vo = v.x; vp = v.y; }
  so[t] = vo; sp[t] = vp; __syncthreads();
  for (int off = 1; off < 1024; off <<= 1) {
    int ao = (t >= off) ? so[t - off] : 0;
    int ap = (t >= off) ? sp[t - off] : 0;
    __syncthreads();
    so[t] += ao; sp[t] += ap;
    __syncthreads();
  }
  if (t < nb) { int2 e; e.x = so[t] - vo; e.y = sp[t] - vp; bsum[t] = e; }
  if (t == 0) *U = so[1023];
}

__global__ __launch_bounds__(BLK) void k_scan3(const int* __restrict__ cnt, int G,
    const int2* __restrict__ bsum, int* __restrict__ rank,
    int* __restrict__ uniq, int* __restrict__ woff) {
  int base = blockIdx.x * SCAN_CHUNK + threadIdx.x * SCAN_ITEMS;
  int so = 0, sp = 0;
  #pragma unroll
  for (int k = 0; k < SCAN_ITEMS; k++) {
    int j = base + k;
    if (j < G) { int c = cnt[j]; if (c > 0) { so++; sp += c; } }
  }
  __shared__ int sho[BLK], shp[BLK];
  sho[threadIdx.x] = so; shp[threadIdx.x] = sp; __syncthreads();
  for (int off = 1; off < BLK; off <<= 1) {
    int ao = (threadIdx.x >= off) ? sho[threadIdx.x - off] : 0;
    int ap = (threadIdx.x >= off) ? shp[threadIdx.x - off] : 0;
    __syncthreads();
    sho[threadIdx.x] += ao; shp[threadIdx.x] += ap;
    __syncthreads();
  }
  int2 bb = bsum[blockIdx.x];
  int ro = bb.x + sho[threadIdx.x] - so;
  int po = bb.y + shp[threadIdx.x] - sp;
  for (int k = 0; k < SCAN_ITEMS; k++) {
    int j = base + k;
    if (j < G) {
      int c = cnt[j];
      if (c > 0) { rank[j] = ro; uniq[ro] = j; woff[ro] = po; ro++; po += c; }
    }
  }
}

// ---------------- counting-sort scatter ----------------
__global__ __launch_bounds__(BLK) void k_scatter(const float* __restrict__ pts,
    const int* __restrict__ rank, int* __restrict__ woff,
    float4* __restrict__ srt, int* __restrict__ jrank,
    int gx, int gy, int gz, float vx, float vy, float vz) {
  int i = blockIdx.x * BLK + threadIdx.x;
  if (i >= NPTS) return;
  float b = pts[i*5+0], x = pts[i*5+1], y = pts[i*5+2], z = pts[i*5+3], it = pts[i*5+4];
  int cx, cy, cz; pcoords(x, y, z, vx, vy, vz, gx, gy, gz, cx, cy, cz);
  int lin = (((int)b * gz + cz) * gy + cy) * gx + cx;
  int r = rank[lin];
  int j = atomicAdd(&woff[r], 1);
  float4 p; p.x = x; p.y = y; p.z = z; p.w = it;
  srt[j] = p;
  jrank[j] = r;
}

// ---------------- per-voxel xyz mean (contiguous reduce) ----------------
__global__ __launch_bounds__(BLK) void k_vox1(const float4* __restrict__ srt,
    const int* __restrict__ uniq, const int* __restrict__ cnt,
    const int* __restrict__ woff, const int* __restrict__ Up,
    float4* __restrict__ vmean) {
  int r = blockIdx.x * BLK + threadIdx.x;
  if (r >= *Up) return;
  int lin = uniq[r];
  int len = cnt[lin];
  int base = woff[r] - len;
  float sx = 0.f, sy = 0.f, sz = 0.f;
  for (int k = 0; k < len; k++) {
    float4 p = srt[base + k];
    sx += p.x; sy += p.y; sz += p.z;
  }
  float il = 1.0f / (float)len;
  float4 o; o.x = sx*il; o.y = sy*il; o.z = sz*il; o.w = il;
  vmean[r] = o;
}

// ---------------- layer 1 matmul: feats(10) @ W1 -> Y (N x C1, sorted) -------
template<int C1>
__global__ __launch_bounds__(BLK) void k_y1(const float4* __restrict__ srt,
    const int* __restrict__ jrank, const float4* __restrict__ vmean,
    const float* __restrict__ W1, float* __restrict__ Y,
    int gx, int gy, int gz, float vx, float vy, float vz) {
  __shared__ float w[10*C1];
  for (int t = threadIdx.x; t < 10*C1; t += BLK) w[t] = W1[t];
  __syncthreads();
  int i = blockIdx.x * BLK + threadIdx.x;
  if (i >= NPTS) return;
  float4 p = srt[i];
  int r = jrank[i];
  float4 vm = vmean[r];
  int cx, cy, cz; pcoords(p.x, p.y, p.z, vx, vy, vz, gx, gy, gz, cx, cy, cz);
  float f[10];
  f[0] = p.x; f[1] = p.y; f[2] = p.z; f[3] = p.w;
  f[4] = p.x - vm.x;
  f[5] = p.y - vm.y;
  f[6] = p.z - vm.z;
  f[7] = p.x - (0.0f   + (cx + 0.5f)*vx);
  f[8] = p.y - (-40.0f + (cy + 0.5f)*vy);
  f[9] = p.z - (-3.0f  + (cz + 0.5f)*vz);
  float* yo = &Y[(size_t)i*C1];
  #pragma unroll
  for (int o = 0; o < C1; o += 4) {
    float a0=0.f, a1=0.f, a2=0.f, a3=0.f;
    #pragma unroll
    for (int k = 0; k < 10; k++) {
      float fv = f[k];
      const float* wr = &w[k*C1 + o];
      a0 = fmaf(fv, wr[0], a0); a1 = fmaf(fv, wr[1], a1);
      a2 = fmaf(fv, wr[2], a2); a3 = fmaf(fv, wr[3], a3);
    }
    float4 v = {a0, a1, a2, a3};
    *(float4*)&yo[o] = v;
  }
}

// ---------------- column sum/sumsq reduction (vectorized, 2048 blocks) ------
template<int C>
__global__ __launch_bounds__(BLK) void k_colreduce(const float* __restrict__ Y,
    float* __restrict__ stats, int rowsPerBlock) {
  constexpr int Q = C / 4;         // float4 quads per row
  constexpr int G = BLK / Q;       // row groups per block
  int q = threadIdx.x & (Q - 1);
  int g = threadIdx.x / Q;
  int i0 = blockIdx.x * rowsPerBlock;
  float s0=0.f,s1=0.f,s2=0.f,s3=0.f, t0=0.f,t1=0.f,t2=0.f,t3=0.f;
  for (int rr = g; rr < rowsPerBlock; rr += G) {
    float4 v = *(const float4*)&Y[(size_t)(i0 + rr)*C + q*4];
    s0 += v.x; s1 += v.y; s2 += v.z; s3 += v.w;
    t0 += v.x*v.x; t1 += v.y*v.y; t2 += v.z*v.z; t3 += v.w*v.w;
  }
  __shared__ float ss[BLK*4], sq[BLK*4];
  int m = threadIdx.x * 4;
  ss[m+0]=s0; ss[m+1]=s1; ss[m+2]=s2; ss[m+3]=s3;
  sq[m+0]=t0; sq[m+1]=t1; sq[m+2]=t2; sq[m+3]=t3;
  __syncthreads();
  for (int off = G/2; off > 0; off >>= 1) {
    if (g < off) {
      int o = ((g + off)*Q + q) * 4;
      ss[m+0]+=ss[o+0]; ss[m+1]+=ss[o+1]; ss[m+2]+=ss[o+2]; ss[m+3]+=ss[o+3];
      sq[m+0]+=sq[o+0]; sq[m+1]+=sq[o+1]; sq[m+2]+=sq[o+2]; sq[m+3]+=sq[o+3];
    }
    __syncthreads();
  }
  if (g == 0) {
    atomicAdd(&stats[q*4+0], ss[m+0]);
    atomicAdd(&stats[q*4+1], ss[m+1]);
    atomicAdd(&stats[q*4+2], ss[m+2]);
    atomicAdd(&stats[q*4+3], ss[m+3]);
    atomicAdd(&stats[C+q*4+0], sq[m+0]);
    atomicAdd(&stats[C+q*4+1], sq[m+1]);
    atomicAdd(&stats[C+q*4+2], sq[m+2]);
    atomicAdd(&stats[C+q*4+3], sq[m+3]);
  }
}

template<int C>
__global__ void k_bncoef(const float* __restrict__ stats, const float* __restrict__ g,
                         const float* __restrict__ b, float* __restrict__ coef) {
  int c = threadIdx.x;
  if (c >= C) return;
  float mu  = stats[c] * (1.0f / NPTS);
  float var = stats[C + c] * (1.0f / NPTS) - mu*mu;
  float sc  = g[c] * (1.0f / sqrtf(var + 1e-3f));
  coef[c]     = sc;
  coef[C + c] = fmaf(-mu, sc, b[c]);
}

// -------- BN+ReLU (optionally in-place H) + per-voxel mean (contiguous) -----
template<int C, bool WRITE_H>
__global__ __launch_bounds__(BLK) void k_hseg(float* __restrict__ Y,
    const float* __restrict__ coef, const int* __restrict__ uniq,
    const int* __restrict__ cnt, const int* __restrict__ woff,
    const int* __restrict__ Up, float* __restrict__ outm) {
  __shared__ float sc[C], sb[C];
  for (int t = threadIdx.x; t < C; t += BLK) { sc[t] = coef[t]; sb[t] = coef[C + t]; }
  __syncthreads();
  constexpr int QPB = C/4;
  int tid = blockIdx.x * BLK + threadIdx.x;
  int r = tid / QPB;
  int q = tid % QPB;
  if (r >= *Up) return;
  int lin = uniq[r];
  int len = cnt[lin];
  int base = woff[r] - len;
  int c0 = q * 4;
  float s0 = sc[c0+0], s1 = sc[c0+1], s2 = sc[c0+2], s3 = sc[c0+3];
  float o0 = sb[c0+0], o1 = sb[c0+1], o2 = sb[c0+2], o3 = sb[c0+3];
  float a0=0.f, a1=0.f, a2=0.f, a3=0.f;
  for (int k = 0; k < len; k++) {
    float* yp = &Y[(size_t)(base + k)*C + c0];
    float4 v = *(float4*)yp;
    float h0 = fmaxf(fmaf(v.x, s0, o0), 0.f);
    float h1 = fmaxf(fmaf(v.y, s1, o1), 0.f);
    float h2 = fmaxf(fmaf(v.z, s2, o2), 0.f);
    float h3 = fmaxf(fmaf(v.w, s3, o3), 0.f);
    if (WRITE_H) { float4 hh = {h0, h1, h2, h3}; *(float4*)yp = hh; }
    a0 += h0; a1 += h1; a2 += h2; a3 += h3;
  }
  float il = 1.0f / (float)len;
  float4 o = {a0*il, a1*il, a2*il, a3*il};
  *(float4*)&outm[(size_t)r*C + c0] = o;
}

// ---------------- layer 2: [h1, segmean1] @ W2 -> Y2 (N x C2, sorted) -------
template<int C1>
__global__ __launch_bounds__(BLK) void k_y2(const float* __restrict__ H1,
    const float* __restrict__ seg1m, const int* __restrict__ jrank,
    const float* __restrict__ W2, float* __restrict__ Y2) {
  constexpr int C2 = 2 * C1;
  __shared__ float w[2*C1*C2];
  for (int t = threadIdx.x*4; t < 2*C1*C2; t += BLK*4)
    *(float4*)&w[t] = *(const float4*)&W2[t];
  __syncthreads();
  int i = blockIdx.x * BLK + threadIdx.x;
  if (i >= NPTS) return;
  int r = jrank[i];
  const float* h1row = &H1[(size_t)i*C1];
  const float* smrow = &seg1m[(size_t)r*C1];
  #pragma unroll 1
  for (int oc = 0; oc < C2; oc += 16) {
    float acc[16];
    #pragma unroll
    for (int j = 0; j < 16; j++) acc[j] = 0.f;
    for (int k = 0; k < C1; k += 4) {
      float4 a = *(const float4*)&h1row[k];
      float av[4] = {a.x, a.y, a.z, a.w};
      #pragma unroll
      for (int kk = 0; kk < 4; kk++) {
        const float* wr = &w[(k + kk)*C2 + oc];
        float4 w0 = *(float4*)&wr[0],  w1 = *(float4*)&wr[4];
        float4 w2 = *(float4*)&wr[8],  w3 = *(float4*)&wr[12];
        float fv = av[kk];
        acc[0]  = fmaf(fv, w0.x, acc[0]);  acc[1]  = fmaf(fv, w0.y, acc[1]);
        acc[2]  = fmaf(fv, w0.z, acc[2]);  acc[3]  = fmaf(fv, w0.w, acc[3]);
        acc[4]  = fmaf(fv, w1.x, acc[4]);  acc[5]  = fmaf(fv, w1.y, acc[5]);
        acc[6]  = fmaf(fv, w1.z, acc[6]);  acc[7]  = fmaf(fv, w1.w, acc[7]);
        acc[8]  = fmaf(fv, w2.x, acc[8]);  acc[9]  = fmaf(fv, w2.y, acc[9]);
        acc[10] = fmaf(fv, w2.z, acc[10]); acc[11] = fmaf(fv, w2.w, acc[11]);
        acc[12] = fmaf(fv, w3.x, acc[12]); acc[13] = fmaf(fv, w3.y, acc[13]);
        acc[14] = fmaf(fv, w3.z, acc[14]); acc[15] = fmaf(fv, w3.w, acc[15]);
      }
    }
    for (int k = 0; k < C1; k += 4) {
      float4 a = *(const float4*)&smrow[k];
      float av[4] = {a.x, a.y, a.z, a.w};
      #pragma unroll
      for (int kk = 0; kk < 4; kk++) {
        const float* wr = &w[(C1 + k + kk)*C2 + oc];
        float4 w0 = *(float4*)&wr[0],  w1 = *(float4*)&wr[4];
        float4 w2 = *(float4*)&wr[8],  w3 = *(float4*)&wr[12];
        float fv = av[kk];
        acc[0]  = fmaf(fv, w0.x, acc[0]);  acc[1]  = fmaf(fv, w0.y, acc[1]);
        acc[2]  = fmaf(fv, w0.z, acc[2]);  acc[3]  = fmaf(fv, w0.w, acc[3]);
        acc[4]  = fmaf(fv, w1.x, acc[4]);  acc[5]  = fmaf(fv, w1.y, acc[5]);
        acc[6]  = fmaf(fv, w1.z, acc[6]);  acc[7]  = fmaf(fv, w1.w, acc[7]);
        acc[8]  = fmaf(fv, w2.x, acc[8]);  acc[9]  = fmaf(fv, w2.y, acc[9]);
        acc[10] = fmaf(fv, w2.z, acc[10]); acc[11] = fmaf(fv, w2.w, acc[11]);
        acc[12] = fmaf(fv, w3.x, acc[12]); acc[13] = fmaf(fv, w3.y, acc[13]);
        acc[14] = fmaf(fv, w3.z, acc[14]); acc[15] = fmaf(fv, w3.w, acc[15]);
      }
    }
    float* yo = &Y2[(size_t)i*C2 + oc];
    float4 out0 = {acc[0], acc[1], acc[2], acc[3]};
    float4 out1 = {acc[4], acc[5], acc[6], acc[7]};
    float4 out2 = {acc[8], acc[9], acc[10], acc[11]};
    float4 out3 = {acc[12], acc[13], acc[14], acc[15]};
    *(float4*)&yo[0] = out0; *(float4*)&yo[4] = out1;
    *(float4*)&yo[8] = out2; *(float4*)&yo[12] = out3;
  }
}

// ---------------- finalize top scale: vf + coors ----------------
__global__ __launch_bounds__(BLK) void k_fin_top(const float* __restrict__ voxfeat,
    const int* __restrict__ uniq, const int* __restrict__ Up,
    float* __restrict__ vf, float* __restrict__ coors) {
  int idx = blockIdx.x * BLK + threadIdx.x;
  int r = idx >> 5;
  int cc = (idx & 31) << 2;
  if (r >= NPTS) return;
  int U = *Up;
  float4 o = {0.f, 0.f, 0.f, 0.f};
  if (r < U) o = *(const float4*)&voxfeat[(size_t)r*128 + cc];
  *(float4*)&vf[(size_t)r*128 + cc] = o;
  if (cc == 0) {
    float4 co;
    if (r < U) {
      int lin = uniq[r];
      int x = lin % TGX; int t = lin / TGX;
      int y = t % TGY;   t /= TGY;
      int z = t % TGZ;   int b = t / TGZ;
      co.x = (float)b; co.y = (float)z; co.z = (float)y; co.w = (float)x;
    } else {
      co.x = -1.f; co.y = -1.f; co.z = -1.f; co.w = -1.f;
    }
    *(float4*)&coors[(size_t)r*4] = co;
  }
}

// ------------- merge: build per-parent child-rank list (gather) -------------
__global__ __launch_bounds__(BLK) void k_clist(const int* __restrict__ tuniq,
    const int* __restrict__ Utp, const int* __restrict__ scnt,
    const int* __restrict__ srank, int* __restrict__ clist, int* __restrict__ mcnt,
    int gx, int gy, int gz, int f) {
  int r = blockIdx.x * BLK + threadIdx.x;
  if (r >= *Utp) return;
  int lin = tuniq[r];
  int x = lin % TGX; int t = lin / TGX;
  int y = t % TGY;   int b = t / TGY;   // TGZ == 1 so z == 0
  int m = 0;
  for (int cz = 0; cz < gz; cz++)
    for (int yy = y*f; yy < y*f + f; yy++)
      for (int xx = x*f; xx < x*f + f; xx++) {
        int cl = ((b*gz + cz)*gy + yy)*gx + xx;
        if (scnt[cl] > 0) clist[(size_t)r*64 + (m++)] = srank[cl];
      }
  mcnt[r] = m;
}

__global__ __launch_bounds__(BLK) void k_merge2(const float* __restrict__ voxfeat,
    const int* __restrict__ clist, const int* __restrict__ mcnt,
    const int* __restrict__ Utp, float* __restrict__ dest) {
  int idx = blockIdx.x * BLK + threadIdx.x;
  int r = idx >> 4;
  int q = idx & 15;
  if (r >= *Utp) return;
  int m = mcnt[r];
  float a0=0.f, a1=0.f, a2=0.f, a3=0.f;
  for (int t = 0; t < m; t++) {
    int cr = clist[(size_t)r*64 + t];
    float4 v = *(const float4*)&voxfeat[(size_t)cr*64 + q*4];
    a0 += v.x; a1 += v.y; a2 += v.z; a3 += v.w;
  }
  float inv = 1.0f / (float)max(m, 1);
  float4 o = {a0*inv, a1*inv, a2*inv, a3*inv};
  *(float4*)&dest[(size_t)r*64 + q*4] = o;
}

// ---------------- final merged compose + tail zero ----------------
__global__ __launch_bounds__(BLK) void k_compose(const float* __restrict__ maccm,
    const float* __restrict__ maccl, const int* __restrict__ Up,
    float* __restrict__ out) {
  int idx = blockIdx.x * BLK + threadIdx.x;
  int r = idx >> 5;
  int q = idx & 31;
  if (r >= NPTS || r >= *Up) return;
  float4 v = (q < 16) ? *(const float4*)&maccm[(size_t)r*64 + q*4]
                      : *(const float4*)&maccl[(size_t)r*64 + (q-16)*4];
  *(float4*)&out[(size_t)r*128 + q*4] = v;
}

__global__ __launch_bounds__(BLK) void k_zerotail(const int* __restrict__ Up,
    float* __restrict__ out) {
  int idx = blockIdx.x * BLK + threadIdx.x;
  int r = idx >> 5;
  int q = idx & 31;
  if (r >= NPTS || r < *Up) return;
  float4 z = {0.f, 0.f, 0.f, 0.f};
  *(float4*)&out[(size_t)r*128 + q*4] = z;
}

// ---------------- one full VFE scale ----------------
template<int C1>
static void run_vfe(hipStream_t stream, const float* pts,
    int G, int gx, int gy, int gz, float vx, float vy, float vz, int UB,
    const float* W1, const float* g1, const float* b1,
    const float* W2, const float* g2, const float* b2,
    int* cntg, int* rankg, int* uniq, int* woff, int2* bsum, int* U,
    float4* srt, int* jrank, float4* vmean,
    float* seg1m, float* voxfeat, float* stats, float* coef,
    float* Y1, float* Y2) {
  constexpr int C2 = 2 * C1;
  (void)hipMemsetAsync(cntg, 0, (size_t)G * 4, stream);
  k_count<<<NPTS/BLK, BLK, 0, stream>>>(pts, cntg, gx, gy, gz, vx, vy, vz);
  int nb = (G + SCAN_CHUNK - 1) / SCAN_CHUNK;
  k_scan1<<<nb, BLK, 0, stream>>>(cntg, G, bsum);
  k_scan2<<<1, 1024, 0, stream>>>(bsum, nb, U);
  k_scan3<<<nb, BLK, 0, stream>>>(cntg, G, bsum, rankg, uniq, woff);
  k_scatter<<<NPTS/BLK, BLK, 0, stream>>>(pts, rankg, woff, srt, jrank, gx, gy, gz, vx, vy, vz);
  k_vox1<<<(UB + BLK - 1)/BLK, BLK, 0, stream>>>(srt, uniq, cntg, woff, U, vmean);
  k_y1<C1><<<NPTS/BLK, BLK, 0, stream>>>(srt, jrank, vmean, W1, Y1, gx, gy, gz, vx, vy, vz);
  (void)hipMemsetAsync(stats, 0, 2 * C1 * sizeof(float), stream);
  k_colreduce<C1><<<2048, BLK, 0, stream>>>(Y1, stats, NPTS/2048);
  k_bncoef<C1><<<1, C1, 0, stream>>>(stats, g1, b1, coef);
  k_hseg<C1, true><<<((size_t)UB*(C1/4) + BLK - 1)/BLK, BLK, 0, stream>>>(
      Y1, coef, uniq, cntg, woff, U, seg1m);
  k_y2<C1><<<NPTS/BLK, BLK, 0, stream>>>(Y1, seg1m, jrank, W2, Y2);
  (void)hipMemsetAsync(stats, 0, 2 * C2 * sizeof(float), stream);
  k_colreduce<C2><<<2048, BLK, 0, stream>>>(Y2, stats, NPTS/2048);
  k_bncoef<C2><<<1, C2, 0, stream>>>(stats, g2, b2, coef);
  k_hseg<C2, false><<<((size_t)UB*(C2/4) + BLK - 1)/BLK, BLK, 0, stream>>>(
      Y2, coef, uniq, cntg, woff, U, voxfeat);
}

extern "C" void kernel_launch(void* const* d_in, const int* in_sizes, int n_in,
                              void* d_out, int out_size, void* d_ws, size_t ws_size,
                              hipStream_t stream) {
  const float* pts = (const float*)d_in[0];
  const float* W1t = (const float*)d_in[2];
  const float* g1t = (const float*)d_in[3];
  const float* b1t = (const float*)d_in[4];
  const float* W2t = (const float*)d_in[5];
  const float* g2t = (const float*)d_in[6];
  const float* b2t = (const float*)d_in[7];
  const float* W1m = (const float*)d_in[8];
  const float* g1m = (const float*)d_in[9];
  const float* b1m = (const float*)d_in[10];
  const float* W2m = (const float*)d_in[11];
  const float* g2m = (const float*)d_in[12];
  const float* b2m = (const float*)d_in[13];
  const float* W1l = (const float*)d_in[14];
  const float* g1l = (const float*)d_in[15];
  const float* b1l = (const float*)d_in[16];
  const float* W2l = (const float*)d_in[17];
  const float* g2l = (const float*)d_in[18];
  const float* b2l = (const float*)d_in[19];

  float* out = (float*)d_out;
  float* vf = out;                              // N x 128
  float* mg = out + (size_t)NPTS * 128;         // N x 128 (also scratch)
  float* co = out + (size_t)NPTS * 256;         // N x 4

  const int G_TOP = 2*1*200*176;     // 70,400
  const int G_MED = 2*2*400*352;     // 1,126,400
  const int G_LOW = 2*4*800*704;     // 4,505,600

  char* w = (char*)d_ws;
  size_t off = 0;
  auto alloc = [&](size_t bytes) -> void* {
    void* p = w + off;
    off = (off + bytes + 1023) & ~(size_t)1023;
    return p;
  };
  int*    top_cnt  = (int*)alloc((size_t)G_TOP * 4);
  int*    top_rank = (int*)alloc((size_t)G_TOP * 4);
  int*    top_uniq = (int*)alloc((size_t)G_TOP * 4);
  int*    big_cnt  = (int*)alloc((size_t)G_LOW * 4);
  int*    big_rank = (int*)alloc((size_t)G_LOW * 4);
  int*    sub_uniq = (int*)alloc((size_t)NPTS * 4);
  int*    woff     = (int*)alloc((size_t)NPTS * 4);
  float4* srt      = (float4*)alloc((size_t)NPTS * 16);
  int*    jrank    = (int*)alloc((size_t)NPTS * 4);
  float4* vmean    = (float4*)alloc((size_t)NPTS * 16);
  float*  seg1m    = (float*)alloc((size_t)NPTS * 32 * 4);   // also clist (18MB<33MB)
  float*  voxfeat  = (float*)alloc((size_t)NPTS * 64 * 4);
  int*    mcnt     = (int*)alloc((size_t)G_TOP * 4);
  float*  maccl    = (float*)alloc((size_t)G_TOP * 64 * 4);
  float*  stats    = (float*)alloc(2 * 128 * 4);
  float*  coef     = (float*)alloc(2 * 128 * 4);
  int2*   bsum     = (int2*)alloc(1024 * 8);
  int*    Utop     = (int*)alloc(64);
  int*    Usub     = (int*)alloc(64);
  (void)in_sizes; (void)n_in; (void)out_size; (void)ws_size;

  float* maccm = mg + (size_t)NPTS * 96;   // lives in mg region rows [0.75N, N)
  int*   clist = (int*)seg1m;              // alias: dead between hseg2 and next scale's hseg1

  // ---- TOP scale (C1=64, C2=128). Y1 in mg region, Y2 in vf region.
  run_vfe<64>(stream, pts, G_TOP, 176, 200, 1, 0.4f, 0.4f, 4.0f, G_TOP,
              W1t, g1t, b1t, W2t, g2t, b2t,
              top_cnt, top_rank, top_uniq, woff, bsum, Utop,
              srt, jrank, vmean, seg1m, voxfeat, stats, coef,
              /*Y1*/ mg, /*Y2*/ vf);
  k_fin_top<<<(NPTS*32)/BLK, BLK, 0, stream>>>(voxfeat, top_uniq, Utop, vf, co);

  // ---- MED scale (C1=32, C2=64). Y1 at mg[0,32N), Y2 at mg[32N,96N).
  run_vfe<32>(stream, pts, G_MED, 352, 400, 2, 0.2f, 0.2f, 2.0f, NPTS,
              W1m, g1m, b1m, W2m, g2m, b2m,
              big_cnt, big_rank, sub_uniq, woff, bsum, Usub,
              srt, jrank, vmean, seg1m, voxfeat, stats, coef,
              /*Y1*/ mg, /*Y2*/ mg + (size_t)NPTS*32);
  k_clist<<<(G_TOP + BLK - 1)/BLK, BLK, 0, stream>>>(top_uniq, Utop, big_cnt, big_rank,
      clist, mcnt, 352, 400, 2, 2);
  k_merge2<<<((size_t)G_TOP*16 + BLK - 1)/BLK, BLK, 0, stream>>>(voxfeat, clist, mcnt,
      Utop, maccm);

  // ---- LOW scale (C1=32, C2=64). Same scratch regions (maccm untouched).
  run_vfe<32>(stream, pts, G_LOW, 704, 800, 4, 0.1f, 0.1f, 1.0f, NPTS,
              W1l, g1l, b1l, W2l, g2l, b2l,
              big_cnt, big_rank, sub_uniq, woff, bsum, Usub,
              srt, jrank, vmean, seg1m, voxfeat, stats, coef,
              /*Y1*/ mg, /*Y2*/ mg + (size_t)NPTS*32);
  k_clist<<<(G_TOP + BLK - 1)/BLK, BLK, 0, stream>>>(top_uniq, Utop, big_cnt, big_rank,
      clist, mcnt, 704, 800, 4, 4);
  k_merge2<<<((size_t)G_TOP*16 + BLK - 1)/BLK, BLK, 0, stream>>>(voxfeat, clist, mcnt,
      Utop, maccl);

  // ---- final merged write: rows < U from macc buffers, then zero the tail.
  k_compose<<<(NPTS*32)/BLK, BLK, 0, stream>>>(maccm, maccl, Utop, mg);
  k_zerotail<<<(NPTS*32)/BLK, BLK, 0, stream>>>(Utop, mg);
}

// Round 4
// 1330.541 us; speedup vs baseline: 1.6619x; 1.6619x over previous
//
#include <hip/hip_runtime.h>
#include <cstdint>
#include <cstddef>

#define NPTS 262144
#define BLK 256
#define TGX 176
#define TGY 200
#define TGZ 1

#define SCAN_ITEMS 32
#define SCAN_CHUNK (BLK*SCAN_ITEMS)
#define CR_BLOCKS 512

// ---------------- voxel coord helpers ----------------
__device__ __forceinline__ void pcoords(float x, float y, float z,
    float vx, float vy, float vz, int gx, int gy, int gz,
    int& cx, int& cy, int& cz) {
  cx = (int)floorf((x - 0.0f)  / vx);
  cy = (int)floorf((y + 40.0f) / vy);
  cz = (int)floorf((z + 3.0f)  / vz);
  cx = min(max(cx, 0), gx - 1);
  cy = min(max(cy, 0), gy - 1);
  cz = min(max(cz, 0), gz - 1);
}

// ---------------- pass 1: dense count grid ----------------
__global__ __launch_bounds__(BLK) void k_count(const float* __restrict__ pts,
    int* __restrict__ cnt, int gx, int gy, int gz, float vx, float vy, float vz) {
  int i = blockIdx.x * BLK + threadIdx.x;
  if (i >= NPTS) return;
  float b = pts[i*5+0], x = pts[i*5+1], y = pts[i*5+2], z = pts[i*5+3];
  int cx, cy, cz; pcoords(x, y, z, vx, vy, vz, gx, gy, gz, cx, cy, cz);
  int lin = (((int)b * gz + cz) * gy + cy) * gx + cx;
  atomicAdd(&cnt[lin], 1);
}

// ---------------- occupancy+count scan (3 phases) ----------------
__global__ __launch_bounds__(BLK) void k_scan1(const int* __restrict__ cnt, int G,
                                               int2* __restrict__ bsum) {
  int base = blockIdx.x * SCAN_CHUNK + threadIdx.x * SCAN_ITEMS;
  int so = 0, sp = 0;
  #pragma unroll
  for (int k = 0; k < SCAN_ITEMS; k++) {
    int j = base + k;
    if (j < G) { int c = cnt[j]; if (c > 0) { so++; sp += c; } }
  }
  __shared__ int sho[BLK], shp[BLK];
  sho[threadIdx.x] = so; shp[threadIdx.x] = sp; __syncthreads();
  for (int off = BLK/2; off > 0; off >>= 1) {
    if (threadIdx.x < off) {
      sho[threadIdx.x] += sho[threadIdx.x + off];
      shp[threadIdx.x] += shp[threadIdx.x + off];
    }
    __syncthreads();
  }
  if (threadIdx.x == 0) { int2 v; v.x = sho[0]; v.y = shp[0]; bsum[blockIdx.x] = v; }
}

__global__ __launch_bounds__(1024) void k_scan2(int2* __restrict__ bsum, int nb,
                                                int* __restrict__ U) {
  __shared__ int so[1024], sp[1024];
  int t = threadIdx.x;
  int vo = 0, vp = 0;
  if (t < nb) { int2 v = bsum[t]; vo = v.x; vp = v.y; }
  so[t] = vo; sp[t] = vp; __syncthreads();
  for (int off = 1; off < 1024; off <<= 1) {
    int ao = (t >= off) ? so[t - off] : 0;
    int ap = (t >= off) ? sp[t - off] : 0;
    __syncthreads();
    so[t] += ao; sp[t] += ap;
    __syncthreads();
  }
  if (t < nb) { int2 e; e.x = so[t] - vo; e.y = sp[t] - vp; bsum[t] = e; }
  if (t == 0) *U = so[1023];
}

__global__ __launch_bounds__(BLK) void k_scan3(const int* __restrict__ cnt, int G,
    const int2* __restrict__ bsum, int* __restrict__ rank,
    int* __restrict__ uniq, int* __restrict__ woff) {
  int base = blockIdx.x * SCAN_CHUNK + threadIdx.x * SCAN_ITEMS;
  int so = 0, sp = 0;
  #pragma unroll
  for (int k = 0; k < SCAN_ITEMS; k++) {
    int j = base + k;
    if (j < G) { int c = cnt[j]; if (c > 0) { so++; sp += c; } }
  }
  __shared__ int sho[BLK], shp[BLK];
  sho[threadIdx.x] = so; shp[threadIdx.x] = sp; __syncthreads();
  for (int off = 1; off < BLK; off <<= 1) {
    int ao = (threadIdx.x >= off) ? sho[threadIdx.x - off] : 0;
    int ap = (threadIdx.x >= off) ? shp[threadIdx.x - off] : 0;
    __syncthreads();
    sho[threadIdx.x] += ao; shp[threadIdx.x] += ap;
    __syncthreads();
  }
  int2 bb = bsum[blockIdx.x];
  int ro = bb.x + sho[threadIdx.x] - so;
  int po = bb.y + shp[threadIdx.x] - sp;
  for (int k = 0; k < SCAN_ITEMS; k++) {
    int j = base + k;
    if (j < G) {
      int c = cnt[j];
      if (c > 0) { rank[j] = ro; uniq[ro] = j; woff[ro] = po; ro++; po += c; }
    }
  }
}

// ---------------- counting-sort scatter ----------------
__global__ __launch_bounds__(BLK) void k_scatter(const float* __restrict__ pts,
    const int* __restrict__ rank, int* __restrict__ woff,
    float4* __restrict__ srt, int* __restrict__ jrank,
    int gx, int gy, int gz, float vx, float vy, float vz) {
  int i = blockIdx.x * BLK + threadIdx.x;
  if (i >= NPTS) return;
  float b = pts[i*5+0], x = pts[i*5+1], y = pts[i*5+2], z = pts[i*5+3], it = pts[i*5+4];
  int cx, cy, cz; pcoords(x, y, z, vx, vy, vz, gx, gy, gz, cx, cy, cz);
  int lin = (((int)b * gz + cz) * gy + cy) * gx + cx;
  int r = rank[lin];
  int j = atomicAdd(&woff[r], 1);
  float4 p; p.x = x; p.y = y; p.z = z; p.w = it;
  srt[j] = p;
  jrank[j] = r;
}

// ---------------- per-voxel xyz mean (contiguous reduce) ----------------
__global__ __launch_bounds__(BLK) void k_vox1(const float4* __restrict__ srt,
    const int* __restrict__ uniq, const int* __restrict__ cnt,
    const int* __restrict__ woff, const int* __restrict__ Up,
    float4* __restrict__ vmean) {
  int r = blockIdx.x * BLK + threadIdx.x;
  if (r >= *Up) return;
  int lin = uniq[r];
  int len = cnt[lin];
  int base = woff[r] - len;
  float sx = 0.f, sy = 0.f, sz = 0.f;
  for (int k = 0; k < len; k++) {
    float4 p = srt[base + k];
    sx += p.x; sy += p.y; sz += p.z;
  }
  float il = 1.0f / (float)len;
  float4 o; o.x = sx*il; o.y = sy*il; o.z = sz*il; o.w = il;
  vmean[r] = o;
}

// ---------------- layer 1 matmul: feats(10) @ W1 -> Y (N x C1, sorted) -------
template<int C1>
__global__ __launch_bounds__(BLK) void k_y1(const float4* __restrict__ srt,
    const int* __restrict__ jrank, const float4* __restrict__ vmean,
    const float* __restrict__ W1, float* __restrict__ Y,
    int gx, int gy, int gz, float vx, float vy, float vz) {
  __shared__ float w[10*C1];
  for (int t = threadIdx.x; t < 10*C1; t += BLK) w[t] = W1[t];
  __syncthreads();
  int i = blockIdx.x * BLK + threadIdx.x;
  if (i >= NPTS) return;
  float4 p = srt[i];
  int r = jrank[i];
  float4 vm = vmean[r];
  int cx, cy, cz; pcoords(p.x, p.y, p.z, vx, vy, vz, gx, gy, gz, cx, cy, cz);
  float f[10];
  f[0] = p.x; f[1] = p.y; f[2] = p.z; f[3] = p.w;
  f[4] = p.x - vm.x;
  f[5] = p.y - vm.y;
  f[6] = p.z - vm.z;
  f[7] = p.x - (0.0f   + (cx + 0.5f)*vx);
  f[8] = p.y - (-40.0f + (cy + 0.5f)*vy);
  f[9] = p.z - (-3.0f  + (cz + 0.5f)*vz);
  float* yo = &Y[(size_t)i*C1];
  #pragma unroll
  for (int o = 0; o < C1; o += 4) {
    float a0=0.f, a1=0.f, a2=0.f, a3=0.f;
    #pragma unroll
    for (int k = 0; k < 10; k++) {
      float fv = f[k];
      const float* wr = &w[k*C1 + o];
      a0 = fmaf(fv, wr[0], a0); a1 = fmaf(fv, wr[1], a1);
      a2 = fmaf(fv, wr[2], a2); a3 = fmaf(fv, wr[3], a3);
    }
    float4 v = {a0, a1, a2, a3};
    *(float4*)&yo[o] = v;
  }
}

// -------- column sum/sumsq partials (atomic-free, CR_BLOCKS blocks) ---------
template<int C>
__global__ __launch_bounds__(BLK) void k_colreduce(const float* __restrict__ Y,
    float* __restrict__ part) {
  constexpr int Q = C / 4;         // float4 quads per row
  constexpr int G = BLK / Q;       // row groups per block
  constexpr int RPB = NPTS / CR_BLOCKS;
  int q = threadIdx.x & (Q - 1);
  int g = threadIdx.x / Q;
  int i0 = blockIdx.x * RPB;
  float s0=0.f,s1=0.f,s2=0.f,s3=0.f, t0=0.f,t1=0.f,t2=0.f,t3=0.f;
  for (int rr = g; rr < RPB; rr += G) {
    float4 v = *(const float4*)&Y[(size_t)(i0 + rr)*C + q*4];
    s0 += v.x; s1 += v.y; s2 += v.z; s3 += v.w;
    t0 += v.x*v.x; t1 += v.y*v.y; t2 += v.z*v.z; t3 += v.w*v.w;
  }
  __shared__ float ss[BLK*4], sq[BLK*4];
  int m = threadIdx.x * 4;
  ss[m+0]=s0; ss[m+1]=s1; ss[m+2]=s2; ss[m+3]=s3;
  sq[m+0]=t0; sq[m+1]=t1; sq[m+2]=t2; sq[m+3]=t3;
  __syncthreads();
  for (int off = G/2; off > 0; off >>= 1) {
    if (g < off) {
      int o = ((g + off)*Q + q) * 4;
      ss[m+0]+=ss[o+0]; ss[m+1]+=ss[o+1]; ss[m+2]+=ss[o+2]; ss[m+3]+=ss[o+3];
      sq[m+0]+=sq[o+0]; sq[m+1]+=sq[o+1]; sq[m+2]+=sq[o+2]; sq[m+3]+=sq[o+3];
    }
    __syncthreads();
  }
  if (g == 0) {
    float* pb = &part[(size_t)blockIdx.x * 2 * C];
    *(float4*)&pb[q*4]     = *(float4*)&ss[m];
    *(float4*)&pb[C + q*4] = *(float4*)&sq[m];
  }
}

// ---- reduce partials -> BN coef (single block; replaces stats+bncoef) ------
template<int C>
__global__ __launch_bounds__(BLK) void k_statcoef(const float* __restrict__ part,
    const float* __restrict__ g, const float* __restrict__ b,
    float* __restrict__ coef) {
  constexpr int NCH = BLK / (2*C) > 0 ? BLK / (2*C) : 1;
  int c = threadIdx.x % (2*C);
  int ch = threadIdx.x / (2*C);
  float s = 0.f;
  for (int bk = ch; bk < CR_BLOCKS; bk += NCH) s += part[(size_t)bk*2*C + c];
  __shared__ float sh[BLK];
  sh[threadIdx.x] = s; __syncthreads();
  for (int off = NCH/2; off > 0; off >>= 1) {
    if (ch < off) sh[threadIdx.x] += sh[threadIdx.x + off*2*C];
    __syncthreads();
  }
  if (ch == 0 && c < C) {
    float mu  = sh[c] * (1.0f / NPTS);
    float var = sh[C + c] * (1.0f / NPTS) - mu*mu;
    float sc  = g[c] * (1.0f / sqrtf(var + 1e-3f));
    coef[c]     = sc;
    coef[C + c] = fmaf(-mu, sc, b[c]);
  }
}

// -------- BN+ReLU + per-voxel mean (contiguous, no H writeback) -------------
template<int C>
__global__ __launch_bounds__(BLK) void k_hseg(const float* __restrict__ Y,
    const float* __restrict__ coef, const int* __restrict__ uniq,
    const int* __restrict__ cnt, const int* __restrict__ woff,
    const int* __restrict__ Up, float* __restrict__ outm) {
  __shared__ float sc[C], sb[C];
  for (int t = threadIdx.x; t < C; t += BLK) { sc[t] = coef[t]; sb[t] = coef[C + t]; }
  __syncthreads();
  constexpr int QPB = C/4;
  int tid = blockIdx.x * BLK + threadIdx.x;
  int r = tid / QPB;
  int q = tid % QPB;
  if (r >= *Up) return;
  int lin = uniq[r];
  int len = cnt[lin];
  int base = woff[r] - len;
  int c0 = q * 4;
  float s0 = sc[c0+0], s1 = sc[c0+1], s2 = sc[c0+2], s3 = sc[c0+3];
  float o0 = sb[c0+0], o1 = sb[c0+1], o2 = sb[c0+2], o3 = sb[c0+3];
  float a0=0.f, a1=0.f, a2=0.f, a3=0.f;
  for (int k = 0; k < len; k++) {
    float4 v = *(const float4*)&Y[(size_t)(base + k)*C + c0];
    a0 += fmaxf(fmaf(v.x, s0, o0), 0.f);
    a1 += fmaxf(fmaf(v.y, s1, o1), 0.f);
    a2 += fmaxf(fmaf(v.z, s2, o2), 0.f);
    a3 += fmaxf(fmaf(v.w, s3, o3), 0.f);
  }
  float il = 1.0f / (float)len;
  float4 o = {a0*il, a1*il, a2*il, a3*il};
  *(float4*)&outm[(size_t)r*C + c0] = o;
}

// ------- layer 2 as LDS-tiled GEMM: A=[BN(Y1)|segmean] (NxK) @ W2 (KxC2) ----
// Block: 64-row tile, full K in LDS (transposed A), B in 64-col panels.
// Thread: 4 rows x 4 cols. LDS = K*64*4 * 2 <= 64 KB.
template<int C1>
__global__ __launch_bounds__(BLK) void k_y2t(const float* __restrict__ Y1,
    const float* __restrict__ coef1, const float* __restrict__ seg1m,
    const int* __restrict__ jrank, const float* __restrict__ W2,
    float* __restrict__ Y2) {
  constexpr int K  = 2*C1;
  constexpr int C2 = 2*C1;
  constexpr int MT = 64;
  constexpr int NT = 64;
  constexpr int NPAN = C2 / NT;
  __shared__ float At[K*MT];   // [k][j]
  __shared__ float Bp[K*NT];   // [k][c]
  const int tid = threadIdx.x;
  const int base = blockIdx.x * MT;

  // ---- stage A-tile transposed, BN+ReLU applied to first half ----
  for (int it = tid; it < MT*(K/4); it += BLK) {
    int j  = it / (K/4);
    int kq = it % (K/4);
    float4 v;
    if (kq < C1/4) {
      v = *(const float4*)&Y1[(size_t)(base + j)*C1 + kq*4];
      v.x = fmaxf(fmaf(v.x, coef1[kq*4+0], coef1[C1+kq*4+0]), 0.f);
      v.y = fmaxf(fmaf(v.y, coef1[kq*4+1], coef1[C1+kq*4+1]), 0.f);
      v.z = fmaxf(fmaf(v.z, coef1[kq*4+2], coef1[C1+kq*4+2]), 0.f);
      v.w = fmaxf(fmaf(v.w, coef1[kq*4+3], coef1[C1+kq*4+3]), 0.f);
    } else {
      int r = jrank[base + j];
      v = *(const float4*)&seg1m[(size_t)r*C1 + (kq - C1/4)*4];
    }
    int k0 = kq*4;
    At[(k0+0)*MT + j] = v.x;
    At[(k0+1)*MT + j] = v.y;
    At[(k0+2)*MT + j] = v.z;
    At[(k0+3)*MT + j] = v.w;
  }

  const int w      = tid >> 6;
  const int lane   = tid & 63;
  const int colg   = lane & 15;
  const int rowsub = lane >> 4;
  const int arow   = w*16 + rowsub*4;   // this thread's first row in tile

  for (int p = 0; p < NPAN; p++) {
    __syncthreads();   // At visible (p=0) / previous panel compute done (p>0)
    for (int it = tid; it < K*(NT/4); it += BLK) {
      int k  = it / (NT/4);
      int cq = it % (NT/4);
      *(float4*)&Bp[k*NT + cq*4] = *(const float4*)&W2[(size_t)k*C2 + p*NT + cq*4];
    }
    __syncthreads();
    float4 ac0 = {0,0,0,0}, ac1 = {0,0,0,0}, ac2 = {0,0,0,0}, ac3 = {0,0,0,0};
    #pragma unroll 8
    for (int k = 0; k < K; k++) {
      float4 a = *(const float4*)&At[k*MT + arow];
      float4 b = *(const float4*)&Bp[k*NT + colg*4];
      ac0.x = fmaf(a.x, b.x, ac0.x); ac0.y = fmaf(a.x, b.y, ac0.y);
      ac0.z = fmaf(a.x, b.z, ac0.z); ac0.w = fmaf(a.x, b.w, ac0.w);
      ac1.x = fmaf(a.y, b.x, ac1.x); ac1.y = fmaf(a.y, b.y, ac1.y);
      ac1.z = fmaf(a.y, b.z, ac1.z); ac1.w = fmaf(a.y, b.w, ac1.w);
      ac2.x = fmaf(a.z, b.x, ac2.x); ac2.y = fmaf(a.z, b.y, ac2.y);
      ac2.z = fmaf(a.z, b.z, ac2.z); ac2.w = fmaf(a.z, b.w, ac2.w);
      ac3.x = fmaf(a.w, b.x, ac3.x); ac3.y = fmaf(a.w, b.y, ac3.y);
      ac3.z = fmaf(a.w, b.z, ac3.z); ac3.w = fmaf(a.w, b.w, ac3.w);
    }
    size_t ob = (size_t)(base + arow)*C2 + p*NT + colg*4;
    *(float4*)&Y2[ob + 0*C2] = ac0;
    *(float4*)&Y2[ob + 1*C2] = ac1;
    *(float4*)&Y2[ob + 2*C2] = ac2;
    *(float4*)&Y2[ob + 3*C2] = ac3;
  }
}

// ---------------- finalize top scale: vf + coors ----------------
__global__ __launch_bounds__(BLK) void k_fin_top(const float* __restrict__ voxfeat,
    const int* __restrict__ uniq, const int* __restrict__ Up,
    float* __restrict__ vf, float* __restrict__ coors) {
  int idx = blockIdx.x * BLK + threadIdx.x;
  int r = idx >> 5;
  int cc = (idx & 31) << 2;
  if (r >= NPTS) return;
  int U = *Up;
  float4 o = {0.f, 0.f, 0.f, 0.f};
  if (r < U) o = *(const float4*)&voxfeat[(size_t)r*128 + cc];
  *(float4*)&vf[(size_t)r*128 + cc] = o;
  if (cc == 0) {
    float4 co;
    if (r < U) {
      int lin = uniq[r];
      int x = lin % TGX; int t = lin / TGX;
      int y = t % TGY;   t /= TGY;
      int z = t % TGZ;   int b = t / TGZ;
      co.x = (float)b; co.y = (float)z; co.z = (float)y; co.w = (float)x;
    } else {
      co.x = -1.f; co.y = -1.f; co.z = -1.f; co.w = -1.f;
    }
    *(float4*)&coors[(size_t)r*4] = co;
  }
}

// ------------- merge: build per-parent child-rank list (gather) -------------
__global__ __launch_bounds__(BLK) void k_clist(const int* __restrict__ tuniq,
    const int* __restrict__ Utp, const int* __restrict__ scnt,
    const int* __restrict__ srank, int* __restrict__ clist, int* __restrict__ mcnt,
    int gx, int gy, int gz, int f) {
  int r = blockIdx.x * BLK + threadIdx.x;
  if (r >= *Utp) return;
  int lin = tuniq[r];
  int x = lin % TGX; int t = lin / TGX;
  int y = t % TGY;   int b = t / TGY;   // TGZ == 1 so z == 0
  int m = 0;
  for (int cz = 0; cz < gz; cz++)
    for (int yy = y*f; yy < y*f + f; yy++)
      for (int xx = x*f; xx < x*f + f; xx++) {
        int cl = ((b*gz + cz)*gy + yy)*gx + xx;
        if (scnt[cl] > 0) clist[(size_t)r*64 + (m++)] = srank[cl];
      }
  mcnt[r] = m;
}

__global__ __launch_bounds__(BLK) void k_merge2(const float* __restrict__ voxfeat,
    const int* __restrict__ clist, const int* __restrict__ mcnt,
    const int* __restrict__ Utp, float* __restrict__ dest) {
  int idx = blockIdx.x * BLK + threadIdx.x;
  int r = idx >> 4;
  int q = idx & 15;
  if (r >= *Utp) return;
  int m = mcnt[r];
  float a0=0.f, a1=0.f, a2=0.f, a3=0.f;
  for (int t = 0; t < m; t++) {
    int cr = clist[(size_t)r*64 + t];
    float4 v = *(const float4*)&voxfeat[(size_t)cr*64 + q*4];
    a0 += v.x; a1 += v.y; a2 += v.z; a3 += v.w;
  }
  float inv = 1.0f / (float)max(m, 1);
  float4 o = {a0*inv, a1*inv, a2*inv, a3*inv};
  *(float4*)&dest[(size_t)r*64 + q*4] = o;
}

// ---------------- final merged compose + tail zero ----------------
__global__ __launch_bounds__(BLK) void k_compose(const float* __restrict__ maccm,
    const float* __restrict__ maccl, const int* __restrict__ Up,
    float* __restrict__ out) {
  int idx = blockIdx.x * BLK + threadIdx.x;
  int r = idx >> 5;
  int q = idx & 31;
  if (r >= NPTS || r >= *Up) return;
  float4 v = (q < 16) ? *(const float4*)&maccm[(size_t)r*64 + q*4]
                      : *(const float4*)&maccl[(size_t)r*64 + (q-16)*4];
  *(float4*)&out[(size_t)r*128 + q*4] = v;
}

__global__ __launch_bounds__(BLK) void k_zerotail(const int* __restrict__ Up,
    float* __restrict__ out) {
  int idx = blockIdx.x * BLK + threadIdx.x;
  int r = idx >> 5;
  int q = idx & 31;
  if (r >= NPTS || r < *Up) return;
  float4 z = {0.f, 0.f, 0.f, 0.f};
  *(float4*)&out[(size_t)r*128 + q*4] = z;
}

// ---------------- one full VFE scale ----------------
template<int C1>
static void run_vfe(hipStream_t stream, const float* pts,
    int G, int gx, int gy, int gz, float vx, float vy, float vz, int UB,
    const float* W1, const float* g1, const float* b1,
    const float* W2, const float* g2, const float* b2,
    int* cntg, int* rankg, int* uniq, int* woff, int2* bsum, int* U,
    float4* srt, int* jrank, float4* vmean,
    float* seg1m, float* voxfeat, float* part, float* coef1, float* coef2,
    float* Y1, float* Y2) {
  constexpr int C2 = 2 * C1;
  (void)hipMemsetAsync(cntg, 0, (size_t)G * 4, stream);
  k_count<<<NPTS/BLK, BLK, 0, stream>>>(pts, cntg, gx, gy, gz, vx, vy, vz);
  int nb = (G + SCAN_CHUNK - 1) / SCAN_CHUNK;
  k_scan1<<<nb, BLK, 0, stream>>>(cntg, G, bsum);
  k_scan2<<<1, 1024, 0, stream>>>(bsum, nb, U);
  k_scan3<<<nb, BLK, 0, stream>>>(cntg, G, bsum, rankg, uniq, woff);
  k_scatter<<<NPTS/BLK, BLK, 0, stream>>>(pts, rankg, woff, srt, jrank, gx, gy, gz, vx, vy, vz);
  k_vox1<<<(UB + BLK - 1)/BLK, BLK, 0, stream>>>(srt, uniq, cntg, woff, U, vmean);
  k_y1<C1><<<NPTS/BLK, BLK, 0, stream>>>(srt, jrank, vmean, W1, Y1, gx, gy, gz, vx, vy, vz);
  k_colreduce<C1><<<CR_BLOCKS, BLK, 0, stream>>>(Y1, part);
  k_statcoef<C1><<<1, BLK, 0, stream>>>(part, g1, b1, coef1);
  k_hseg<C1><<<((size_t)UB*(C1/4) + BLK - 1)/BLK, BLK, 0, stream>>>(
      Y1, coef1, uniq, cntg, woff, U, seg1m);
  k_y2t<C1><<<NPTS/64, BLK, 0, stream>>>(Y1, coef1, seg1m, jrank, W2, Y2);
  k_colreduce<C2><<<CR_BLOCKS, BLK, 0, stream>>>(Y2, part);
  k_statcoef<C2><<<1, BLK, 0, stream>>>(part, g2, b2, coef2);
  k_hseg<C2><<<((size_t)UB*(C2/4) + BLK - 1)/BLK, BLK, 0, stream>>>(
      Y2, coef2, uniq, cntg, woff, U, voxfeat);
}

extern "C" void kernel_launch(void* const* d_in, const int* in_sizes, int n_in,
                              void* d_out, int out_size, void* d_ws, size_t ws_size,
                              hipStream_t stream) {
  const float* pts = (const float*)d_in[0];
  const float* W1t = (const float*)d_in[2];
  const float* g1t = (const float*)d_in[3];
  const float* b1t = (const float*)d_in[4];
  const float* W2t = (const float*)d_in[5];
  const float* g2t = (const float*)d_in[6];
  const float* b2t = (const float*)d_in[7];
  const float* W1m = (const float*)d_in[8];
  const float* g1m = (const float*)d_in[9];
  const float* b1m = (const float*)d_in[10];
  const float* W2m = (const float*)d_in[11];
  const float* g2m = (const float*)d_in[12];
  const float* b2m = (const float*)d_in[13];
  const float* W1l = (const float*)d_in[14];
  const float* g1l = (const float*)d_in[15];
  const float* b1l = (const float*)d_in[16];
  const float* W2l = (const float*)d_in[17];
  const float* g2l = (const float*)d_in[18];
  const float* b2l = (const float*)d_in[19];

  float* out = (float*)d_out;
  float* vf = out;                              // N x 128
  float* mg = out + (size_t)NPTS * 128;         // N x 128 (also scratch)
  float* co = out + (size_t)NPTS * 256;         // N x 4

  const int G_TOP = 2*1*200*176;     // 70,400
  const int G_MED = 2*2*400*352;     // 1,126,400
  const int G_LOW = 2*4*800*704;     // 4,505,600

  char* w = (char*)d_ws;
  size_t off = 0;
  auto alloc = [&](size_t bytes) -> void* {
    void* p = w + off;
    off = (off + bytes + 1023) & ~(size_t)1023;
    return p;
  };
  int*    top_cnt  = (int*)alloc((size_t)G_TOP * 4);
  int*    top_rank = (int*)alloc((size_t)G_TOP * 4);
  int*    top_uniq = (int*)alloc((size_t)G_TOP * 4);
  int*    big_cnt  = (int*)alloc((size_t)G_LOW * 4);
  int*    big_rank = (int*)alloc((size_t)G_LOW * 4);
  int*    sub_uniq = (int*)alloc((size_t)NPTS * 4);
  int*    woff     = (int*)alloc((size_t)NPTS * 4);
  float4* srt      = (float4*)alloc((size_t)NPTS * 16);
  int*    jrank    = (int*)alloc((size_t)NPTS * 4);
  float4* vmean    = (float4*)alloc((size_t)NPTS * 16);
  float*  seg1m    = (float*)alloc((size_t)NPTS * 32 * 4);   // also clist alias
  float*  voxfeat  = (float*)alloc((size_t)NPTS * 64 * 4);
  int*    mcnt     = (int*)alloc((size_t)G_TOP * 4);
  float*  maccl    = (float*)alloc((size_t)G_TOP * 64 * 4);
  float*  part     = (float*)alloc((size_t)CR_BLOCKS * 256 * 4);
  float*  coef1    = (float*)alloc(2 * 128 * 4);
  float*  coef2    = (float*)alloc(2 * 128 * 4);
  int2*   bsum     = (int2*)alloc(1024 * 8);
  int*    Utop     = (int*)alloc(64);
  int*    Usub     = (int*)alloc(64);
  (void)in_sizes; (void)n_in; (void)out_size; (void)ws_size;

  float* maccm = mg + (size_t)NPTS * 96;   // lives in mg region rows [0.75N, N)
  int*   clist = (int*)seg1m;              // alias: dead between hseg2 and next hseg1

  // ---- TOP scale (C1=64, C2=128). Y1 in mg region, Y2 in vf region.
  run_vfe<64>(stream, pts, G_TOP, 176, 200, 1, 0.4f, 0.4f, 4.0f, G_TOP,
              W1t, g1t, b1t, W2t, g2t, b2t,
              top_cnt, top_rank, top_uniq, woff, bsum, Utop,
              srt, jrank, vmean, seg1m, voxfeat, part, coef1, coef2,
              /*Y1*/ mg, /*Y2*/ vf);
  k_fin_top<<<(NPTS*32)/BLK, BLK, 0, stream>>>(voxfeat, top_uniq, Utop, vf, co);

  // ---- MED scale (C1=32, C2=64). Y1 at mg[0,32N), Y2 at mg[32N,96N).
  run_vfe<32>(stream, pts, G_MED, 352, 400, 2, 0.2f, 0.2f, 2.0f, NPTS,
              W1m, g1m, b1m, W2m, g2m, b2m,
              big_cnt, big_rank, sub_uniq, woff, bsum, Usub,
              srt, jrank, vmean, seg1m, voxfeat, part, coef1, coef2,
              /*Y1*/ mg, /*Y2*/ mg + (size_t)NPTS*32);
  k_clist<<<(G_TOP + BLK - 1)/BLK, BLK, 0, stream>>>(top_uniq, Utop, big_cnt, big_rank,
      clist, mcnt, 352, 400, 2, 2);
  k_merge2<<<((size_t)G_TOP*16 + BLK - 1)/BLK, BLK, 0, stream>>>(voxfeat, clist, mcnt,
      Utop, maccm);

  // ---- LOW scale (C1=32, C2=64). Same scratch regions (maccm untouched).
  run_vfe<32>(stream, pts, G_LOW, 704, 800, 4, 0.1f, 0.1f, 1.0f, NPTS,
              W1l, g1l, b1l, W2l, g2l, b2l,
              big_cnt, big_rank, sub_uniq, woff, bsum, Usub,
              srt, jrank, vmean, seg1m, voxfeat, part, coef1, coef2,
              /*Y1*/ mg, /*Y2*/ mg + (size_t)NPTS*32);
  k_clist<<<(G_TOP + BLK - 1)/BLK, BLK, 0, stream>>>(top_uniq, Utop, big_cnt, big_rank,
      clist, mcnt, 704, 800, 4, 4);
  k_merge2<<<((size_t)G_TOP*16 + BLK - 1)/BLK, BLK, 0, stream>>>(voxfeat, clist, mcnt,
      Utop, maccl);

  // ---- final merged write: rows < U from macc buffers, then zero the tail.
  k_compose<<<(NPTS*32)/BLK, BLK, 0, stream>>>(maccm, maccl, Utop, mg);
  k_zerotail<<<(NPTS*32)/BLK, BLK, 0, stream>>>(Utop, mg);
}

// Round 5
// 934.983 us; speedup vs baseline: 2.3650x; 1.4231x over previous
//
#include <hip/hip_runtime.h>
#include <cstdint>
#include <cstddef>

#define NPTS 262144
#define BLK 256
#define TGX 176
#define TGY 200
#define TGZ 1

#define SCAN_ITEMS 32
#define SCAN_CHUNK (BLK*SCAN_ITEMS)
#define CR_CH 16            // chunks per channel for layer-1 col reduction
#define Y2BLKS (NPTS/64)    // 4096 blocks for y2t

// ---------------- voxel coord helpers ----------------
__device__ __forceinline__ void pcoords(float x, float y, float z,
    float vx, float vy, float vz, int gx, int gy, int gz,
    int& cx, int& cy, int& cz) {
  cx = (int)floorf((x - 0.0f)  / vx);
  cy = (int)floorf((y + 40.0f) / vy);
  cz = (int)floorf((z + 3.0f)  / vz);
  cx = min(max(cx, 0), gx - 1);
  cy = min(max(cy, 0), gy - 1);
  cz = min(max(cz, 0), gz - 1);
}

// ---------------- pass 1: dense count grid ----------------
__global__ __launch_bounds__(BLK) void k_count(const float* __restrict__ pts,
    int* __restrict__ cnt, int gx, int gy, int gz, float vx, float vy, float vz) {
  int i = blockIdx.x * BLK + threadIdx.x;
  if (i >= NPTS) return;
  float b = pts[i*5+0], x = pts[i*5+1], y = pts[i*5+2], z = pts[i*5+3];
  int cx, cy, cz; pcoords(x, y, z, vx, vy, vz, gx, gy, gz, cx, cy, cz);
  int lin = (((int)b * gz + cz) * gy + cy) * gx + cx;
  atomicAdd(&cnt[lin], 1);
}

// ---------------- occupancy+count scan (3 phases) ----------------
__global__ __launch_bounds__(BLK) void k_scan1(const int* __restrict__ cnt, int G,
                                               int2* __restrict__ bsum) {
  int base = blockIdx.x * SCAN_CHUNK + threadIdx.x * SCAN_ITEMS;
  int so = 0, sp = 0;
  #pragma unroll
  for (int k = 0; k < SCAN_ITEMS; k++) {
    int j = base + k;
    if (j < G) { int c = cnt[j]; if (c > 0) { so++; sp += c; } }
  }
  __shared__ int sho[BLK], shp[BLK];
  sho[threadIdx.x] = so; shp[threadIdx.x] = sp; __syncthreads();
  for (int off = BLK/2; off > 0; off >>= 1) {
    if (threadIdx.x < off) {
      sho[threadIdx.x] += sho[threadIdx.x + off];
      shp[threadIdx.x] += shp[threadIdx.x + off];
    }
    __syncthreads();
  }
  if (threadIdx.x == 0) { int2 v; v.x = sho[0]; v.y = shp[0]; bsum[blockIdx.x] = v; }
}

__global__ __launch_bounds__(1024) void k_scan2(int2* __restrict__ bsum, int nb,
                                                int* __restrict__ U) {
  __shared__ int so[1024], sp[1024];
  int t = threadIdx.x;
  int vo = 0, vp = 0;
  if (t < nb) { int2 v = bsum[t]; vo = v.x; vp = v.y; }
  so[t] = vo; sp[t] = vp; __syncthreads();
  for (int off = 1; off < 1024; off <<= 1) {
    int ao = (t >= off) ? so[t - off] : 0;
    int ap = (t >= off) ? sp[t - off] : 0;
    __syncthreads();
    so[t] += ao; sp[t] += ap;
    __syncthreads();
  }
  if (t < nb) { int2 e; e.x = so[t] - vo; e.y = sp[t] - vp; bsum[t] = e; }
  if (t == 0) *U = so[1023];
}

__global__ __launch_bounds__(BLK) void k_scan3(const int* __restrict__ cnt, int G,
    const int2* __restrict__ bsum, int* __restrict__ rank,
    int* __restrict__ uniq, int* __restrict__ woff) {
  int base = blockIdx.x * SCAN_CHUNK + threadIdx.x * SCAN_ITEMS;
  int so = 0, sp = 0;
  #pragma unroll
  for (int k = 0; k < SCAN_ITEMS; k++) {
    int j = base + k;
    if (j < G) { int c = cnt[j]; if (c > 0) { so++; sp += c; } }
  }
  __shared__ int sho[BLK], shp[BLK];
  sho[threadIdx.x] = so; shp[threadIdx.x] = sp; __syncthreads();
  for (int off = 1; off < BLK; off <<= 1) {
    int ao = (threadIdx.x >= off) ? sho[threadIdx.x - off] : 0;
    int ap = (threadIdx.x >= off) ? shp[threadIdx.x - off] : 0;
    __syncthreads();
    sho[threadIdx.x] += ao; shp[threadIdx.x] += ap;
    __syncthreads();
  }
  int2 bb = bsum[blockIdx.x];
  int ro = bb.x + sho[threadIdx.x] - so;
  int po = bb.y + shp[threadIdx.x] - sp;
  for (int k = 0; k < SCAN_ITEMS; k++) {
    int j = base + k;
    if (j < G) {
      int c = cnt[j];
      if (c > 0) { rank[j] = ro; uniq[ro] = j; woff[ro] = po; ro++; po += c; }
    }
  }
}

// ---------------- counting-sort scatter ----------------
__global__ __launch_bounds__(BLK) void k_scatter(const float* __restrict__ pts,
    const int* __restrict__ rank, int* __restrict__ woff,
    float4* __restrict__ srt, int* __restrict__ jrank,
    int gx, int gy, int gz, float vx, float vy, float vz) {
  int i = blockIdx.x * BLK + threadIdx.x;
  if (i >= NPTS) return;
  float b = pts[i*5+0], x = pts[i*5+1], y = pts[i*5+2], z = pts[i*5+3], it = pts[i*5+4];
  int cx, cy, cz; pcoords(x, y, z, vx, vy, vz, gx, gy, gz, cx, cy, cz);
  int lin = (((int)b * gz + cz) * gy + cy) * gx + cx;
  int r = rank[lin];
  int j = atomicAdd(&woff[r], 1);
  float4 p; p.x = x; p.y = y; p.z = z; p.w = it;
  srt[j] = p;
  jrank[j] = r;
}

// ---------------- per-voxel xyz mean (contiguous reduce) ----------------
__global__ __launch_bounds__(BLK) void k_vox1(const float4* __restrict__ srt,
    const int* __restrict__ uniq, const int* __restrict__ cnt,
    const int* __restrict__ woff, const int* __restrict__ Up,
    float4* __restrict__ vmean) {
  int r = blockIdx.x * BLK + threadIdx.x;
  if (r >= *Up) return;
  int lin = uniq[r];
  int len = cnt[lin];
  int base = woff[r] - len;
  float sx = 0.f, sy = 0.f, sz = 0.f;
  for (int k = 0; k < len; k++) {
    float4 p = srt[base + k];
    sx += p.x; sy += p.y; sz += p.z;
  }
  float il = 1.0f / (float)len;
  float4 o; o.x = sx*il; o.y = sy*il; o.z = sz*il; o.w = il;
  vmean[r] = o;
}

// ------ layer 1 matmul: feats(10) @ W1 -> Y1t (C1 x N, channel-major) -------
template<int C1>
__global__ __launch_bounds__(BLK) void k_y1T(const float4* __restrict__ srt,
    const int* __restrict__ jrank, const float4* __restrict__ vmean,
    const float* __restrict__ W1, float* __restrict__ Y1t,
    int gx, int gy, int gz, float vx, float vy, float vz) {
  __shared__ float w[10*C1];
  for (int t = threadIdx.x; t < 10*C1; t += BLK) w[t] = W1[t];
  __syncthreads();
  int i = blockIdx.x * BLK + threadIdx.x;
  if (i >= NPTS) return;
  float4 p = srt[i];
  int r = jrank[i];
  float4 vm = vmean[r];
  int cx, cy, cz; pcoords(p.x, p.y, p.z, vx, vy, vz, gx, gy, gz, cx, cy, cz);
  float f[10];
  f[0] = p.x; f[1] = p.y; f[2] = p.z; f[3] = p.w;
  f[4] = p.x - vm.x;
  f[5] = p.y - vm.y;
  f[6] = p.z - vm.z;
  f[7] = p.x - (0.0f   + (cx + 0.5f)*vx);
  f[8] = p.y - (-40.0f + (cy + 0.5f)*vy);
  f[9] = p.z - (-3.0f  + (cz + 0.5f)*vz);
  #pragma unroll
  for (int o = 0; o < C1; o += 4) {
    float a0=0.f, a1=0.f, a2=0.f, a3=0.f;
    #pragma unroll
    for (int k = 0; k < 10; k++) {
      float fv = f[k];
      const float* wr = &w[k*C1 + o];
      a0 = fmaf(fv, wr[0], a0); a1 = fmaf(fv, wr[1], a1);
      a2 = fmaf(fv, wr[2], a2); a3 = fmaf(fv, wr[3], a3);
    }
    Y1t[(size_t)(o+0)*NPTS + i] = a0;
    Y1t[(size_t)(o+1)*NPTS + i] = a1;
    Y1t[(size_t)(o+2)*NPTS + i] = a2;
    Y1t[(size_t)(o+3)*NPTS + i] = a3;
  }
}

// ---- layer-1 stats: contiguous channel-row chunks (atomic-free) ------------
__global__ __launch_bounds__(BLK) void k_colreduceT(const float* __restrict__ Y1t,
    float* __restrict__ part) {
  int c  = blockIdx.x / CR_CH;
  int ch = blockIdx.x % CR_CH;
  const float* row = &Y1t[(size_t)c*NPTS + (size_t)ch*(NPTS/CR_CH)];
  float s = 0.f, q = 0.f;
  for (int i = threadIdx.x*4; i < NPTS/CR_CH; i += BLK*4) {
    float4 v = *(const float4*)&row[i];
    s += v.x + v.y + v.z + v.w;
    q += v.x*v.x + v.y*v.y + v.z*v.z + v.w*v.w;
  }
  __shared__ float ss[BLK], sq[BLK];
  ss[threadIdx.x] = s; sq[threadIdx.x] = q; __syncthreads();
  for (int off = BLK/2; off > 0; off >>= 1) {
    if (threadIdx.x < off) {
      ss[threadIdx.x] += ss[threadIdx.x + off];
      sq[threadIdx.x] += sq[threadIdx.x + off];
    }
    __syncthreads();
  }
  if (threadIdx.x == 0) {
    part[(size_t)blockIdx.x*2 + 0] = ss[0];
    part[(size_t)blockIdx.x*2 + 1] = sq[0];
  }
}

template<int C>
__global__ void k_statcoef1(const float* __restrict__ part,
    const float* __restrict__ g, const float* __restrict__ b,
    float* __restrict__ coef) {
  int c = threadIdx.x;
  if (c >= C) return;
  float s = 0.f, q = 0.f;
  for (int ch = 0; ch < CR_CH; ch++) {
    s += part[(size_t)(c*CR_CH + ch)*2 + 0];
    q += part[(size_t)(c*CR_CH + ch)*2 + 1];
  }
  float mu  = s * (1.0f / NPTS);
  float var = q * (1.0f / NPTS) - mu*mu;
  float sc  = g[c] * (1.0f / sqrtf(var + 1e-3f));
  coef[c]     = sc;
  coef[C + c] = fmaf(-mu, sc, b[c]);
}

// ---- layer-1 BN+ReLU + voxel mean -> segt (C1 x segstride, transposed) -----
template<int C1>
__global__ __launch_bounds__(BLK) void k_hsegT(const float* __restrict__ Y1t,
    const float* __restrict__ coef, const int* __restrict__ uniq,
    const int* __restrict__ cnt, const int* __restrict__ woff,
    const int* __restrict__ Up, float* __restrict__ segt, int segstride) {
  constexpr int QPB = C1/4;
  int tid = blockIdx.x * BLK + threadIdx.x;
  int r = tid / QPB;
  int q = tid % QPB;
  if (r >= *Up) return;
  int lin = uniq[r];
  int len = cnt[lin];
  int base = woff[r] - len;
  int c0 = q * 4;
  float s0 = coef[c0+0], s1 = coef[c0+1], s2 = coef[c0+2], s3 = coef[c0+3];
  float o0 = coef[C1+c0+0], o1 = coef[C1+c0+1], o2 = coef[C1+c0+2], o3 = coef[C1+c0+3];
  const float* p0 = &Y1t[(size_t)(c0+0)*NPTS + base];
  const float* p1 = &Y1t[(size_t)(c0+1)*NPTS + base];
  const float* p2 = &Y1t[(size_t)(c0+2)*NPTS + base];
  const float* p3 = &Y1t[(size_t)(c0+3)*NPTS + base];
  float a0=0.f, a1=0.f, a2=0.f, a3=0.f;
  for (int k = 0; k < len; k++) {
    a0 += fmaxf(fmaf(p0[k], s0, o0), 0.f);
    a1 += fmaxf(fmaf(p1[k], s1, o1), 0.f);
    a2 += fmaxf(fmaf(p2[k], s2, o2), 0.f);
    a3 += fmaxf(fmaf(p3[k], s3, o3), 0.f);
  }
  float il = 1.0f / (float)len;
  segt[(size_t)(c0+0)*segstride + r] = a0*il;
  segt[(size_t)(c0+1)*segstride + r] = a1*il;
  segt[(size_t)(c0+2)*segstride + r] = a2*il;
  segt[(size_t)(c0+3)*segstride + r] = a3*il;
}

// ------- layer 2 LDS-tiled GEMM + fused column-stat partials ----------------
// A = [BN(Y1t) | segmeanT] gathered conflict-free; 64-row tile; 64-col panels.
template<int C1>
__global__ __launch_bounds__(BLK) void k_y2t(const float* __restrict__ Y1t,
    const float* __restrict__ coef1, const float* __restrict__ segt, int segstride,
    const int* __restrict__ jrank, const float* __restrict__ W2,
    float* __restrict__ Y2, float* __restrict__ part) {
  constexpr int K  = 2*C1;
  constexpr int C2 = 2*C1;
  constexpr int MT = 64;
  constexpr int NT = 64;
  constexpr int NPAN = C2 / NT;
  __shared__ float At[K*MT];   // [k][j] — also reused as reduction scratch
  __shared__ float Bp[K*NT];   // [k][c]
  __shared__ int jrl[MT];
  const int tid = threadIdx.x;
  const int base = blockIdx.x * MT;

  if (tid < MT) jrl[tid] = jrank[base + tid];
  // Y1 half: contiguous float4 rows, BN+ReLU inline. Dense banks, no conflict.
  for (int it = tid; it < C1*(MT/4); it += BLK) {
    int k  = it >> 4;
    int j4 = (it & 15) << 2;
    float4 v = *(const float4*)&Y1t[(size_t)k*NPTS + base + j4];
    float s = coef1[k], o = coef1[C1 + k];
    v.x = fmaxf(fmaf(v.x, s, o), 0.f);
    v.y = fmaxf(fmaf(v.y, s, o), 0.f);
    v.z = fmaxf(fmaf(v.z, s, o), 0.f);
    v.w = fmaxf(fmaf(v.w, s, o), 0.f);
    *(float4*)&At[k*MT + j4] = v;
  }
  __syncthreads();   // jrl visible
  // seg half: consecutive-scalar stores (conflict-free); jrl is monotone -> near-coalesced gather
  for (int it = tid; it < C1*MT; it += BLK) {
    int c = it >> 6;
    int j = it & 63;
    At[(C1 + c)*MT + j] = segt[(size_t)c*segstride + jrl[j]];
  }

  const int w      = tid >> 6;
  const int lane   = tid & 63;
  const int colg   = lane & 15;
  const int rowsub = lane >> 4;
  const int arow   = w*16 + rowsub*4;

  float cs[NPAN][4], cq[NPAN][4];
  #pragma unroll
  for (int p = 0; p < NPAN; p++) {
    __syncthreads();   // At ready (p=0) / previous panel compute done
    for (int it = tid; it < K*(NT/4); it += BLK) {
      int k  = it >> 4;
      int cq4 = (it & 15) << 2;
      *(float4*)&Bp[k*NT + cq4] = *(const float4*)&W2[(size_t)k*C2 + p*NT + cq4];
    }
    __syncthreads();
    float4 ac0 = {0,0,0,0}, ac1 = {0,0,0,0}, ac2 = {0,0,0,0}, ac3 = {0,0,0,0};
    #pragma unroll 8
    for (int k = 0; k < K; k++) {
      float4 a = *(const float4*)&At[k*MT + arow];
      float4 b = *(const float4*)&Bp[k*NT + colg*4];
      ac0.x = fmaf(a.x, b.x, ac0.x); ac0.y = fmaf(a.x, b.y, ac0.y);
      ac0.z = fmaf(a.x, b.z, ac0.z); ac0.w = fmaf(a.x, b.w, ac0.w);
      ac1.x = fmaf(a.y, b.x, ac1.x); ac1.y = fmaf(a.y, b.y, ac1.y);
      ac1.z = fmaf(a.y, b.z, ac1.z); ac1.w = fmaf(a.y, b.w, ac1.w);
      ac2.x = fmaf(a.z, b.x, ac2.x); ac2.y = fmaf(a.z, b.y, ac2.y);
      ac2.z = fmaf(a.z, b.z, ac2.z); ac2.w = fmaf(a.z, b.w, ac2.w);
      ac3.x = fmaf(a.w, b.x, ac3.x); ac3.y = fmaf(a.w, b.y, ac3.y);
      ac3.z = fmaf(a.w, b.z, ac3.z); ac3.w = fmaf(a.w, b.w, ac3.w);
    }
    cs[p][0] = ac0.x + ac1.x + ac2.x + ac3.x;
    cs[p][1] = ac0.y + ac1.y + ac2.y + ac3.y;
    cs[p][2] = ac0.z + ac1.z + ac2.z + ac3.z;
    cs[p][3] = ac0.w + ac1.w + ac2.w + ac3.w;
    cq[p][0] = ac0.x*ac0.x + ac1.x*ac1.x + ac2.x*ac2.x + ac3.x*ac3.x;
    cq[p][1] = ac0.y*ac0.y + ac1.y*ac1.y + ac2.y*ac2.y + ac3.y*ac3.y;
    cq[p][2] = ac0.z*ac0.z + ac1.z*ac1.z + ac2.z*ac2.z + ac3.z*ac3.z;
    cq[p][3] = ac0.w*ac0.w + ac1.w*ac1.w + ac2.w*ac2.w + ac3.w*ac3.w;
    size_t ob = (size_t)(base + arow)*C2 + p*NT + colg*4;
    *(float4*)&Y2[ob + 0*C2] = ac0;
    *(float4*)&Y2[ob + 1*C2] = ac1;
    *(float4*)&Y2[ob + 2*C2] = ac2;
    *(float4*)&Y2[ob + 3*C2] = ac3;
  }

  // ---- fused per-block column sum/sumsq partials (reuse At as scratch) ----
  __syncthreads();
  float* red = At;                 // [32][C2+1]: rows 0..15 sums, 16..31 sq
  const int contrib = w*4 + rowsub;
  #pragma unroll
  for (int p = 0; p < NPAN; p++) {
    #pragma unroll
    for (int e = 0; e < 4; e++) {
      red[contrib*(C2+1) + p*NT + colg*4 + e]        = cs[p][e];
      red[(16 + contrib)*(C2+1) + p*NT + colg*4 + e] = cq[p][e];
    }
  }
  __syncthreads();
  if (tid < C2) {
    float s = 0.f, q = 0.f;
    #pragma unroll 4
    for (int i = 0; i < 16; i++) {
      s += red[i*(C2+1) + tid];
      q += red[(16 + i)*(C2+1) + tid];
    }
    part[(size_t)blockIdx.x*2*C2 + tid]      = s;
    part[(size_t)blockIdx.x*2*C2 + C2 + tid] = q;
  }
}

// ---- reduce y2t partials: one block per column ----
__global__ __launch_bounds__(BLK) void k_partred(const float* __restrict__ part,
    int nb, int twoC, float* __restrict__ stats2) {
  int c = blockIdx.x;
  float s = 0.f;
  for (int bk = threadIdx.x; bk < nb; bk += BLK) s += part[(size_t)bk*twoC + c];
  __shared__ float sh[BLK];
  sh[threadIdx.x] = s; __syncthreads();
  for (int off = BLK/2; off > 0; off >>= 1) {
    if (threadIdx.x < off) sh[threadIdx.x] += sh[threadIdx.x + off];
    __syncthreads();
  }
  if (threadIdx.x == 0) stats2[c] = sh[0];
}

template<int C>
__global__ void k_coeffin(const float* __restrict__ stats2,
    const float* __restrict__ g, const float* __restrict__ b,
    float* __restrict__ coef) {
  int c = threadIdx.x;
  if (c >= C) return;
  float mu  = stats2[c] * (1.0f / NPTS);
  float var = stats2[C + c] * (1.0f / NPTS) - mu*mu;
  float sc  = g[c] * (1.0f / sqrtf(var + 1e-3f));
  coef[c]     = sc;
  coef[C + c] = fmaf(-mu, sc, b[c]);
}

// -------- layer-2 BN+ReLU + voxel mean (row-major Y2, compact out) ----------
template<int C>
__global__ __launch_bounds__(BLK) void k_hseg2(const float* __restrict__ Y,
    const float* __restrict__ coef, const int* __restrict__ uniq,
    const int* __restrict__ cnt, const int* __restrict__ woff,
    const int* __restrict__ Up, float* __restrict__ outm) {
  __shared__ float sc[C], sb[C];
  for (int t = threadIdx.x; t < C; t += BLK) { sc[t] = coef[t]; sb[t] = coef[C + t]; }
  __syncthreads();
  constexpr int QPB = C/4;
  int tid = blockIdx.x * BLK + threadIdx.x;
  int r = tid / QPB;
  int q = tid % QPB;
  if (r >= *Up) return;
  int lin = uniq[r];
  int len = cnt[lin];
  int base = woff[r] - len;
  int c0 = q * 4;
  float s0 = sc[c0+0], s1 = sc[c0+1], s2 = sc[c0+2], s3 = sc[c0+3];
  float o0 = sb[c0+0], o1 = sb[c0+1], o2 = sb[c0+2], o3 = sb[c0+3];
  float a0=0.f, a1=0.f, a2=0.f, a3=0.f;
  for (int k = 0; k < len; k++) {
    float4 v = *(const float4*)&Y[(size_t)(base + k)*C + c0];
    a0 += fmaxf(fmaf(v.x, s0, o0), 0.f);
    a1 += fmaxf(fmaf(v.y, s1, o1), 0.f);
    a2 += fmaxf(fmaf(v.z, s2, o2), 0.f);
    a3 += fmaxf(fmaf(v.w, s3, o3), 0.f);
  }
  float il = 1.0f / (float)len;
  float4 o = {a0*il, a1*il, a2*il, a3*il};
  *(float4*)&outm[(size_t)r*C + c0] = o;
}

// ---------------- finalize top scale: vf + coors ----------------
__global__ __launch_bounds__(BLK) void k_fin_top(const float* __restrict__ voxfeat,
    const int* __restrict__ uniq, const int* __restrict__ Up,
    float* __restrict__ vf, float* __restrict__ coors) {
  int idx = blockIdx.x * BLK + threadIdx.x;
  int r = idx >> 5;
  int cc = (idx & 31) << 2;
  if (r >= NPTS) return;
  int U = *Up;
  float4 o = {0.f, 0.f, 0.f, 0.f};
  if (r < U) o = *(const float4*)&voxfeat[(size_t)r*128 + cc];
  *(float4*)&vf[(size_t)r*128 + cc] = o;
  if (cc == 0) {
    float4 co;
    if (r < U) {
      int lin = uniq[r];
      int x = lin % TGX; int t = lin / TGX;
      int y = t % TGY;   t /= TGY;
      int z = t % TGZ;   int b = t / TGZ;
      co.x = (float)b; co.y = (float)z; co.z = (float)y; co.w = (float)x;
    } else {
      co.x = -1.f; co.y = -1.f; co.z = -1.f; co.w = -1.f;
    }
    *(float4*)&coors[(size_t)r*4] = co;
  }
}

// ------------- merge: build per-parent child-rank list (gather) -------------
__global__ __launch_bounds__(BLK) void k_clist(const int* __restrict__ tuniq,
    const int* __restrict__ Utp, const int* __restrict__ scnt,
    const int* __restrict__ srank, int* __restrict__ clist, int* __restrict__ mcnt,
    int gx, int gy, int gz, int f) {
  int r = blockIdx.x * BLK + threadIdx.x;
  if (r >= *Utp) return;
  int lin = tuniq[r];
  int x = lin % TGX; int t = lin / TGX;
  int y = t % TGY;   int b = t / TGY;   // TGZ == 1 so z == 0
  int m = 0;
  for (int cz = 0; cz < gz; cz++)
    for (int yy = y*f; yy < y*f + f; yy++)
      for (int xx = x*f; xx < x*f + f; xx++) {
        int cl = ((b*gz + cz)*gy + yy)*gx + xx;
        if (scnt[cl] > 0) clist[(size_t)r*64 + (m++)] = srank[cl];
      }
  mcnt[r] = m;
}

__global__ __launch_bounds__(BLK) void k_merge2(const float* __restrict__ voxfeat,
    const int* __restrict__ clist, const int* __restrict__ mcnt,
    const int* __restrict__ Utp, float* __restrict__ dest) {
  int idx = blockIdx.x * BLK + threadIdx.x;
  int r = idx >> 4;
  int q = idx & 15;
  if (r >= *Utp) return;
  int m = mcnt[r];
  float a0=0.f, a1=0.f, a2=0.f, a3=0.f;
  for (int t = 0; t < m; t++) {
    int cr = clist[(size_t)r*64 + t];
    float4 v = *(const float4*)&voxfeat[(size_t)cr*64 + q*4];
    a0 += v.x; a1 += v.y; a2 += v.z; a3 += v.w;
  }
  float inv = 1.0f / (float)max(m, 1);
  float4 o = {a0*inv, a1*inv, a2*inv, a3*inv};
  *(float4*)&dest[(size_t)r*64 + q*4] = o;
}

// ---------------- final merged compose + tail zero ----------------
__global__ __launch_bounds__(BLK) void k_compose(const float* __restrict__ maccm,
    const float* __restrict__ maccl, const int* __restrict__ Up,
    float* __restrict__ out) {
  int idx = blockIdx.x * BLK + threadIdx.x;
  int r = idx >> 5;
  int q = idx & 31;
  if (r >= NPTS || r >= *Up) return;
  float4 v = (q < 16) ? *(const float4*)&maccm[(size_t)r*64 + q*4]
                      : *(const float4*)&maccl[(size_t)r*64 + (q-16)*4];
  *(float4*)&out[(size_t)r*128 + q*4] = v;
}

__global__ __launch_bounds__(BLK) void k_zerotail(const int* __restrict__ Up,
    float* __restrict__ out) {
  int idx = blockIdx.x * BLK + threadIdx.x;
  int r = idx >> 5;
  int q = idx & 31;
  if (r >= NPTS || r < *Up) return;
  float4 z = {0.f, 0.f, 0.f, 0.f};
  *(float4*)&out[(size_t)r*128 + q*4] = z;
}

// ---------------- one full VFE scale ----------------
template<int C1>
static void run_vfe(hipStream_t stream, const float* pts,
    int G, int gx, int gy, int gz, float vx, float vy, float vz,
    int UB, int segstride,
    const float* W1, const float* g1, const float* b1,
    const float* W2, const float* g2, const float* b2,
    int* cntg, int* rankg, int* uniq, int* woff, int2* bsum, int* U,
    float4* srt, int* jrank, float4* vmean,
    float* segt, float* voxfeat, float* part, float* stats2,
    float* coef1, float* coef2, float* Y1t, float* Y2) {
  constexpr int C2 = 2 * C1;
  (void)hipMemsetAsync(cntg, 0, (size_t)G * 4, stream);
  k_count<<<NPTS/BLK, BLK, 0, stream>>>(pts, cntg, gx, gy, gz, vx, vy, vz);
  int nb = (G + SCAN_CHUNK - 1) / SCAN_CHUNK;
  k_scan1<<<nb, BLK, 0, stream>>>(cntg, G, bsum);
  k_scan2<<<1, 1024, 0, stream>>>(bsum, nb, U);
  k_scan3<<<nb, BLK, 0, stream>>>(cntg, G, bsum, rankg, uniq, woff);
  k_scatter<<<NPTS/BLK, BLK, 0, stream>>>(pts, rankg, woff, srt, jrank, gx, gy, gz, vx, vy, vz);
  k_vox1<<<(UB + BLK - 1)/BLK, BLK, 0, stream>>>(srt, uniq, cntg, woff, U, vmean);
  k_y1T<C1><<<NPTS/BLK, BLK, 0, stream>>>(srt, jrank, vmean, W1, Y1t, gx, gy, gz, vx, vy, vz);
  k_colreduceT<<<C1*CR_CH, BLK, 0, stream>>>(Y1t, part);
  k_statcoef1<C1><<<1, BLK, 0, stream>>>(part, g1, b1, coef1);
  k_hsegT<C1><<<((size_t)UB*(C1/4) + BLK - 1)/BLK, BLK, 0, stream>>>(
      Y1t, coef1, uniq, cntg, woff, U, segt, segstride);
  k_y2t<C1><<<Y2BLKS, BLK, 0, stream>>>(Y1t, coef1, segt, segstride, jrank, W2, Y2, part);
  k_partred<<<2*C2, BLK, 0, stream>>>(part, Y2BLKS, 2*C2, stats2);
  k_coeffin<C2><<<1, BLK, 0, stream>>>(stats2, g2, b2, coef2);
  k_hseg2<C2><<<((size_t)UB*(C2/4) + BLK - 1)/BLK, BLK, 0, stream>>>(
      Y2, coef2, uniq, cntg, woff, U, voxfeat);
}

extern "C" void kernel_launch(void* const* d_in, const int* in_sizes, int n_in,
                              void* d_out, int out_size, void* d_ws, size_t ws_size,
                              hipStream_t stream) {
  const float* pts = (const float*)d_in[0];
  const float* W1t = (const float*)d_in[2];
  const float* g1t = (const float*)d_in[3];
  const float* b1t = (const float*)d_in[4];
  const float* W2t = (const float*)d_in[5];
  const float* g2t = (const float*)d_in[6];
  const float* b2t = (const float*)d_in[7];
  const float* W1m = (const float*)d_in[8];
  const float* g1m = (const float*)d_in[9];
  const float* b1m = (const float*)d_in[10];
  const float* W2m = (const float*)d_in[11];
  const float* g2m = (const float*)d_in[12];
  const float* b2m = (const float*)d_in[13];
  const float* W1l = (const float*)d_in[14];
  const float* g1l = (const float*)d_in[15];
  const float* b1l = (const float*)d_in[16];
  const float* W2l = (const float*)d_in[17];
  const float* g2l = (const float*)d_in[18];
  const float* b2l = (const float*)d_in[19];

  float* out = (float*)d_out;
  float* vf = out;                              // N x 128
  float* mg = out + (size_t)NPTS * 128;         // N x 128 (also scratch)
  float* co = out + (size_t)NPTS * 256;         // N x 4

  const int G_TOP = 2*1*200*176;     // 70,400
  const int G_MED = 2*2*400*352;     // 1,126,400
  const int G_LOW = 2*4*800*704;     // 4,505,600

  char* w = (char*)d_ws;
  size_t off = 0;
  auto alloc = [&](size_t bytes) -> void* {
    void* p = w + off;
    off = (off + bytes + 1023) & ~(size_t)1023;
    return p;
  };
  int*    top_cnt  = (int*)alloc((size_t)G_TOP * 4);
  int*    top_rank = (int*)alloc((size_t)G_TOP * 4);
  int*    top_uniq = (int*)alloc((size_t)G_TOP * 4);
  int*    big_cnt  = (int*)alloc((size_t)G_LOW * 4);
  int*    big_rank = (int*)alloc((size_t)G_LOW * 4);
  int*    sub_uniq = (int*)alloc((size_t)NPTS * 4);
  int*    woff     = (int*)alloc((size_t)NPTS * 4);
  float4* srt      = (float4*)alloc((size_t)NPTS * 16);
  int*    jrank    = (int*)alloc((size_t)NPTS * 4);
  float4* vmean    = (float4*)alloc((size_t)NPTS * 16);
  float*  segt     = (float*)alloc((size_t)NPTS * 32 * 4);   // also clist alias
  float*  voxfeat  = (float*)alloc((size_t)NPTS * 64 * 4);
  int*    mcnt     = (int*)alloc((size_t)G_TOP * 4);
  float*  maccl    = (float*)alloc((size_t)G_TOP * 64 * 4);
  float*  part     = (float*)alloc((size_t)Y2BLKS * 256 * 4);  // 4 MB
  float*  stats2   = (float*)alloc(2 * 128 * 4);
  float*  coef1    = (float*)alloc(2 * 128 * 4);
  float*  coef2    = (float*)alloc(2 * 128 * 4);
  int2*   bsum     = (int2*)alloc(1024 * 8);
  int*    Utop     = (int*)alloc(64);
  int*    Usub     = (int*)alloc(64);
  (void)in_sizes; (void)n_in; (void)out_size; (void)ws_size;

  float* maccm = mg + (size_t)NPTS * 96;   // mg rows [0.75N, N)
  int*   clist = (int*)segt;               // alias: dead between hseg2 and next hsegT

  // ---- TOP scale (C1=64, C2=128). Y1t (64 x N) in mg, Y2 in vf region.
  run_vfe<64>(stream, pts, G_TOP, 176, 200, 1, 0.4f, 0.4f, 4.0f, G_TOP, G_TOP,
              W1t, g1t, b1t, W2t, g2t, b2t,
              top_cnt, top_rank, top_uniq, woff, bsum, Utop,
              srt, jrank, vmean, segt, voxfeat, part, stats2, coef1, coef2,
              /*Y1t*/ mg, /*Y2*/ vf);
  k_fin_top<<<(NPTS*32)/BLK, BLK, 0, stream>>>(voxfeat, top_uniq, Utop, vf, co);

  // ---- MED scale (C1=32, C2=64). Y1t (32 x N) at mg[0,32N), Y2 at mg[32N,96N).
  run_vfe<32>(stream, pts, G_MED, 352, 400, 2, 0.2f, 0.2f, 2.0f, NPTS, NPTS,
              W1m, g1m, b1m, W2m, g2m, b2m,
              big_cnt, big_rank, sub_uniq, woff, bsum, Usub,
              srt, jrank, vmean, segt, voxfeat, part, stats2, coef1, coef2,
              /*Y1t*/ mg, /*Y2*/ mg + (size_t)NPTS*32);
  k_clist<<<(G_TOP + BLK - 1)/BLK, BLK, 0, stream>>>(top_uniq, Utop, big_cnt, big_rank,
      clist, mcnt, 352, 400, 2, 2);
  k_merge2<<<((size_t)G_TOP*16 + BLK - 1)/BLK, BLK, 0, stream>>>(voxfeat, clist, mcnt,
      Utop, maccm);

  // ---- LOW scale (C1=32, C2=64). Same scratch regions (maccm untouched).
  run_vfe<32>(stream, pts, G_LOW, 704, 800, 4, 0.1f, 0.1f, 1.0f, NPTS, NPTS,
              W1l, g1l, b1l, W2l, g2l, b2l,
              big_cnt, big_rank, sub_uniq, woff, bsum, Usub,
              srt, jrank, vmean, segt, voxfeat, part, stats2, coef1, coef2,
              /*Y1t*/ mg, /*Y2*/ mg + (size_t)NPTS*32);
  k_clist<<<(G_TOP + BLK - 1)/BLK, BLK, 0, stream>>>(top_uniq, Utop, big_cnt, big_rank,
      clist, mcnt, 704, 800, 4, 4);
  k_merge2<<<((size_t)G_TOP*16 + BLK - 1)/BLK, BLK, 0, stream>>>(voxfeat, clist, mcnt,
      Utop, maccl);

  // ---- final merged write: rows < U from macc buffers, then zero the tail.
  k_compose<<<(NPTS*32)/BLK, BLK, 0, stream>>>(maccm, maccl, Utop, mg);
  k_zerotail<<<(NPTS*32)/BLK, BLK, 0, stream>>>(Utop, mg);
}

// Round 7
// 831.276 us; speedup vs baseline: 2.6600x; 1.1248x over previous
//
#include <hip/hip_runtime.h>
#include <cstdint>
#include <cstddef>

#define NPTS 262144
#define BLK 256
#define TGX 176
#define TGY 200
#define TGZ 1

#define G_TOPC 70400
#define G_MEDC 1126400
#define G_LOWC 4505600

#define SCAN_ITEMS 32
#define SCAN_CHUNK (BLK*SCAN_ITEMS)
// batched scan block counts / bsum offsets (disjoint: [0,9) [16,154) [160,710))
#define NB_T 9
#define NB_M 138
#define NB_L 550
#define BO_T 0
#define BO_M 16
#define BO_L 160
// vox13 block split
#define NBVT (G_TOPC/BLK)      // 275
#define NBVM (NPTS/BLK)        // 1024
#define NBVL (NPTS/BLK)        // 1024

#define Y2BLKS (NPTS/64)       // 4096
#define ST1BLKS 256            // stats1 blocks (1024 rows each)

// ---------------- voxel coord helpers ----------------
__device__ __forceinline__ void pcoords(float x, float y, float z,
    float vx, float vy, float vz, int gx, int gy, int gz,
    int& cx, int& cy, int& cz) {
  cx = (int)floorf((x - 0.0f)  / vx);
  cy = (int)floorf((y + 40.0f) / vy);
  cz = (int)floorf((z + 3.0f)  / vz);
  cx = min(max(cx, 0), gx - 1);
  cy = min(max(cy, 0), gy - 1);
  cz = min(max(cz, 0), gz - 1);
}

__device__ __forceinline__ int lin3(float b, float x, float y, float z,
    float vx, float vy, float vz, int gx, int gy, int gz) {
  int cx, cy, cz; pcoords(x, y, z, vx, vy, vz, gx, gy, gz, cx, cy, cz);
  return (((int)b * gz + cz) * gy + cy) * gx + cx;
}

// f-vector (10 features) — identical expression everywhere y1 is recomputed.
__device__ __forceinline__ void build_f(float4 p, float4 vm,
    float vx, float vy, float vz, int gx, int gy, int gz, float* f) {
  int cx, cy, cz; pcoords(p.x, p.y, p.z, vx, vy, vz, gx, gy, gz, cx, cy, cz);
  f[0] = p.x; f[1] = p.y; f[2] = p.z; f[3] = p.w;
  f[4] = p.x - vm.x;
  f[5] = p.y - vm.y;
  f[6] = p.z - vm.z;
  f[7] = p.x - (0.0f   + (cx + 0.5f)*vx);
  f[8] = p.y - (-40.0f + (cy + 0.5f)*vy);
  f[9] = p.z - (-3.0f  + (cz + 0.5f)*vz);
}

// ---------------- batched dense count (all 3 scales) ----------------
__global__ __launch_bounds__(BLK) void k_count3(const float* __restrict__ pts,
    int* __restrict__ ct, int* __restrict__ cm, int* __restrict__ cl) {
  int i = blockIdx.x * BLK + threadIdx.x;
  if (i >= NPTS) return;
  float b = pts[i*5+0], x = pts[i*5+1], y = pts[i*5+2], z = pts[i*5+3];
  atomicAdd(&ct[lin3(b,x,y,z, 0.4f,0.4f,4.0f, 176,200,1)], 1);
  atomicAdd(&cm[lin3(b,x,y,z, 0.2f,0.2f,2.0f, 352,400,2)], 1);
  atomicAdd(&cl[lin3(b,x,y,z, 0.1f,0.1f,1.0f, 704,800,4)], 1);
}

// ---------------- batched scans ----------------
__global__ __launch_bounds__(BLK) void k_scan1_all(const int* __restrict__ ct,
    const int* __restrict__ cm, const int* __restrict__ cl,
    int2* __restrict__ bsum) {
  int bid = blockIdx.x;
  const int* cnt; int G, bo, cb;
  if (bid < NB_T)            { cnt = ct; G = G_TOPC; bo = BO_T; cb = bid; }
  else if (bid < NB_T+NB_M)  { cnt = cm; G = G_MEDC; bo = BO_M; cb = bid - NB_T; }
  else                       { cnt = cl; G = G_LOWC; bo = BO_L; cb = bid - NB_T - NB_M; }
  int base = cb * SCAN_CHUNK + threadIdx.x * SCAN_ITEMS;
  int so = 0, sp = 0;
  #pragma unroll
  for (int k = 0; k < SCAN_ITEMS; k++) {
    int j = base + k;
    if (j < G) { int c = cnt[j]; if (c > 0) { so++; sp += c; } }
  }
  __shared__ int sho[BLK], shp[BLK];
  sho[threadIdx.x] = so; shp[threadIdx.x] = sp; __syncthreads();
  for (int off = BLK/2; off > 0; off >>= 1) {
    if (threadIdx.x < off) {
      sho[threadIdx.x] += sho[threadIdx.x + off];
      shp[threadIdx.x] += shp[threadIdx.x + off];
    }
    __syncthreads();
  }
  if (threadIdx.x == 0) { int2 v; v.x = sho[0]; v.y = shp[0]; bsum[bo + cb] = v; }
}

__device__ void scan_pass(int2* bsum, int off, int nb, int* U,
                          int* so, int* sp) {
  int t = threadIdx.x;
  int vo = 0, vp = 0;
  if (t < nb) { int2 v = bsum[off + t]; vo = v.x; vp = v.y; }
  so[t] = vo; sp[t] = vp; __syncthreads();
  for (int o = 1; o < 1024; o <<= 1) {
    int ao = (t >= o) ? so[t - o] : 0;
    int ap = (t >= o) ? sp[t - o] : 0;
    __syncthreads();
    so[t] += ao; sp[t] += ap;
    __syncthreads();
  }
  if (t < nb) { int2 e; e.x = so[t] - vo; e.y = sp[t] - vp; bsum[off + t] = e; }
  if (t == 0) *U = so[1023];
  __syncthreads();
}

__global__ __launch_bounds__(1024) void k_scan2_all(int2* __restrict__ bsum,
    int* __restrict__ Ut, int* __restrict__ Um, int* __restrict__ Ul) {
  __shared__ int so[1024], sp[1024];
  scan_pass(bsum, BO_T, NB_T, Ut, so, sp);
  scan_pass(bsum, BO_M, NB_M, Um, so, sp);
  scan_pass(bsum, BO_L, NB_L, Ul, so, sp);
}

__global__ __launch_bounds__(BLK) void k_scan3_all(const int* __restrict__ ct,
    const int* __restrict__ cm, const int* __restrict__ cl,
    const int2* __restrict__ bsum,
    int* __restrict__ rkt, int* __restrict__ rkm, int* __restrict__ rkl,
    int* __restrict__ uqt, int* __restrict__ uqm, int* __restrict__ uql,
    int* __restrict__ wot, int* __restrict__ wom, int* __restrict__ wol) {
  int bid = blockIdx.x;
  const int* cnt; int G, bo, cb; int *rank, *uniq, *woff;
  if (bid < NB_T)           { cnt=ct; G=G_TOPC; bo=BO_T; cb=bid;            rank=rkt; uniq=uqt; woff=wot; }
  else if (bid < NB_T+NB_M) { cnt=cm; G=G_MEDC; bo=BO_M; cb=bid-NB_T;       rank=rkm; uniq=uqm; woff=wom; }
  else                      { cnt=cl; G=G_LOWC; bo=BO_L; cb=bid-NB_T-NB_M;  rank=rkl; uniq=uql; woff=wol; }
  int base = cb * SCAN_CHUNK + threadIdx.x * SCAN_ITEMS;
  int so = 0, sp = 0;
  #pragma unroll
  for (int k = 0; k < SCAN_ITEMS; k++) {
    int j = base + k;
    if (j < G) { int c = cnt[j]; if (c > 0) { so++; sp += c; } }
  }
  __shared__ int sho[BLK], shp[BLK];
  sho[threadIdx.x] = so; shp[threadIdx.x] = sp; __syncthreads();
  for (int off = 1; off < BLK; off <<= 1) {
    int ao = (threadIdx.x >= off) ? sho[threadIdx.x - off] : 0;
    int ap = (threadIdx.x >= off) ? shp[threadIdx.x - off] : 0;
    __syncthreads();
    sho[threadIdx.x] += ao; shp[threadIdx.x] += ap;
    __syncthreads();
  }
  int2 bb = bsum[bo + cb];
  int ro = bb.x + sho[threadIdx.x] - so;
  int po = bb.y + shp[threadIdx.x] - sp;
  for (int k = 0; k < SCAN_ITEMS; k++) {
    int j = base + k;
    if (j < G) {
      int c = cnt[j];
      if (c > 0) { rank[j] = ro; uniq[ro] = j; woff[ro] = po; ro++; po += c; }
    }
  }
}

// ---------------- batched counting-sort scatter ----------------
__global__ __launch_bounds__(BLK) void k_scatter3(const float* __restrict__ pts,
    const int* __restrict__ rkt, int* __restrict__ wot, float4* __restrict__ st, int* __restrict__ jt,
    const int* __restrict__ rkm, int* __restrict__ wom, float4* __restrict__ sm, int* __restrict__ jm,
    const int* __restrict__ rkl, int* __restrict__ wol, float4* __restrict__ sl, int* __restrict__ jl) {
  int i = blockIdx.x * BLK + threadIdx.x;
  if (i >= NPTS) return;
  float b = pts[i*5+0], x = pts[i*5+1], y = pts[i*5+2], z = pts[i*5+3], it = pts[i*5+4];
  float4 p; p.x = x; p.y = y; p.z = z; p.w = it;
  {
    int r = rkt[lin3(b,x,y,z, 0.4f,0.4f,4.0f, 176,200,1)];
    int j = atomicAdd(&wot[r], 1); st[j] = p; jt[j] = r;
  }
  {
    int r = rkm[lin3(b,x,y,z, 0.2f,0.2f,2.0f, 352,400,2)];
    int j = atomicAdd(&wom[r], 1); sm[j] = p; jm[j] = r;
  }
  {
    int r = rkl[lin3(b,x,y,z, 0.1f,0.1f,1.0f, 704,800,4)];
    int j = atomicAdd(&wol[r], 1); sl[j] = p; jl[j] = r;
  }
}

// ---------------- batched per-voxel xyz means ----------------
__global__ __launch_bounds__(BLK) void k_vox13(
    const float4* __restrict__ st, const int* __restrict__ uqt, const int* __restrict__ ct,
    const int* __restrict__ wot, const int* __restrict__ Ut, float4* __restrict__ vt,
    const float4* __restrict__ sm, const int* __restrict__ uqm, const int* __restrict__ cm,
    const int* __restrict__ wom, const int* __restrict__ Um, float4* __restrict__ vm,
    const float4* __restrict__ sl, const int* __restrict__ uql, const int* __restrict__ cl,
    const int* __restrict__ wol, const int* __restrict__ Ul, float4* __restrict__ vl) {
  int bid = blockIdx.x;
  const float4* srt; const int *uniq, *cnt, *woff, *Up; float4* vmean; int r;
  if (bid < NBVT)           { r = bid*BLK + threadIdx.x;           srt=st; uniq=uqt; cnt=ct; woff=wot; Up=Ut; vmean=vt; }
  else if (bid < NBVT+NBVM) { r = (bid-NBVT)*BLK + threadIdx.x;    srt=sm; uniq=uqm; cnt=cm; woff=wom; Up=Um; vmean=vm; }
  else                      { r = (bid-NBVT-NBVM)*BLK + threadIdx.x; srt=sl; uniq=uql; cnt=cl; woff=wol; Up=Ul; vmean=vl; }
  if (r >= *Up) return;
  int lin = uniq[r];
  int len = cnt[lin];
  int base = woff[r] - len;
  float sx = 0.f, sy = 0.f, sz = 0.f;
  for (int k = 0; k < len; k++) {
    float4 p = srt[base + k];
    sx += p.x; sy += p.y; sz += p.z;
  }
  float il = 1.0f / (float)len;
  float4 o; o.x = sx*il; o.y = sy*il; o.z = sz*il; o.w = il;
  vmean[r] = o;
}

// ------- fused y1-compute + column sum/sumsq partials (no Y1 write) ---------
template<int C1>
__global__ __launch_bounds__(BLK) void k_stats1(const float4* __restrict__ srt,
    const int* __restrict__ jrank, const float4* __restrict__ vmean,
    const float* __restrict__ W1, float* __restrict__ part,
    int gx, int gy, int gz, float vx, float vy, float vz) {
  __shared__ float w[10*C1];
  __shared__ float wsum[4][C1], wsq[4][C1];
  for (int t = threadIdx.x; t < 10*C1; t += BLK) w[t] = W1[t];
  __syncthreads();
  float f[4][10];
  #pragma unroll
  for (int k = 0; k < 4; k++) {
    int i = blockIdx.x*1024 + k*BLK + threadIdx.x;
    float4 p = srt[i];
    float4 vmn = vmean[jrank[i]];
    build_f(p, vmn, vx, vy, vz, gx, gy, gz, f[k]);
  }
  int wv = threadIdx.x >> 6;
  int lane = threadIdx.x & 63;
  for (int o = 0; o < C1; o += 4) {
    float s[4] = {0,0,0,0}, q[4] = {0,0,0,0};
    #pragma unroll
    for (int k = 0; k < 4; k++) {
      float a0=0.f, a1=0.f, a2=0.f, a3=0.f;
      #pragma unroll
      for (int d = 0; d < 10; d++) {
        float fv = f[k][d];
        const float* wr = &w[d*C1 + o];
        a0 = fmaf(fv, wr[0], a0); a1 = fmaf(fv, wr[1], a1);
        a2 = fmaf(fv, wr[2], a2); a3 = fmaf(fv, wr[3], a3);
      }
      s[0] += a0; s[1] += a1; s[2] += a2; s[3] += a3;
      q[0] += a0*a0; q[1] += a1*a1; q[2] += a2*a2; q[3] += a3*a3;
    }
    #pragma unroll
    for (int m = 1; m < 64; m <<= 1) {
      #pragma unroll
      for (int e = 0; e < 4; e++) {
        s[e] += __shfl_xor(s[e], m);
        q[e] += __shfl_xor(q[e], m);
      }
    }
    if (lane == 0) {
      #pragma unroll
      for (int e = 0; e < 4; e++) { wsum[wv][o+e] = s[e]; wsq[wv][o+e] = q[e]; }
    }
  }
  __syncthreads();
  if (threadIdx.x < C1) {
    int c = threadIdx.x;
    float s = wsum[0][c] + wsum[1][c] + wsum[2][c] + wsum[3][c];
    float q = wsq[0][c] + wsq[1][c] + wsq[2][c] + wsq[3][c];
    part[(size_t)blockIdx.x*2*C1 + c]      = s;
    part[(size_t)blockIdx.x*2*C1 + C1 + c] = q;
  }
}

// ---- reduce per-block partials -> BN coef (grid = C blocks) ----------------
template<int C>
__global__ __launch_bounds__(BLK) void k_partcoef(const float* __restrict__ part,
    int NB, const float* __restrict__ g, const float* __restrict__ b,
    float* __restrict__ coef) {
  int c = blockIdx.x;
  float s = 0.f, q = 0.f;
  for (int bk = threadIdx.x; bk < NB; bk += BLK) {
    s += part[(size_t)bk*2*C + c];
    q += part[(size_t)bk*2*C + C + c];
  }
  __shared__ float ss[BLK], sq[BLK];
  ss[threadIdx.x] = s; sq[threadIdx.x] = q; __syncthreads();
  for (int off = BLK/2; off > 0; off >>= 1) {
    if (threadIdx.x < off) {
      ss[threadIdx.x] += ss[threadIdx.x + off];
      sq[threadIdx.x] += sq[threadIdx.x + off];
    }
    __syncthreads();
  }
  if (threadIdx.x == 0) {
    float mu  = ss[0] * (1.0f / NPTS);
    float var = sq[0] * (1.0f / NPTS) - mu*mu;
    float sc  = g[c] * (1.0f / sqrtf(var + 1e-3f));
    coef[c]     = sc;
    coef[C + c] = fmaf(-mu, sc, b[c]);
  }
}

// ---- layer-1 voxel means of BN+ReLU(y1), y1 recomputed from points ---------
template<int C1>
__global__ __launch_bounds__(BLK) void k_hsegT(const float4* __restrict__ srt,
    const float4* __restrict__ vmean, const float* __restrict__ W1,
    const float* __restrict__ coef, const int* __restrict__ uniq,
    const int* __restrict__ cnt, const int* __restrict__ woff,
    const int* __restrict__ Up, float* __restrict__ segt, int segstride,
    int gx, int gy, int gz, float vx, float vy, float vz) {
  __shared__ float w[10*C1];
  __shared__ float sc[C1], sb[C1];
  for (int t = threadIdx.x; t < 10*C1; t += BLK) w[t] = W1[t];
  for (int t = threadIdx.x; t < C1; t += BLK) { sc[t] = coef[t]; sb[t] = coef[C1 + t]; }
  __syncthreads();
  constexpr int QPB = C1/4;
  int tid = blockIdx.x * BLK + threadIdx.x;
  int r = tid / QPB;
  int q = tid % QPB;
  if (r >= *Up) return;
  int lin = uniq[r];
  int len = cnt[lin];
  int base = woff[r] - len;
  float4 vmn = vmean[r];
  int c0 = q * 4;
  float s0 = sc[c0+0], s1 = sc[c0+1], s2 = sc[c0+2], s3 = sc[c0+3];
  float o0 = sb[c0+0], o1 = sb[c0+1], o2 = sb[c0+2], o3 = sb[c0+3];
  float a0=0.f, a1=0.f, a2=0.f, a3=0.f;
  for (int k = 0; k < len; k++) {
    float4 p = srt[base + k];
    float f[10];
    build_f(p, vmn, vx, vy, vz, gx, gy, gz, f);
    float y0=0.f, y1=0.f, y2=0.f, y3=0.f;
    #pragma unroll
    for (int d = 0; d < 10; d++) {
      float fv = f[d];
      const float* wr = &w[d*C1 + c0];
      y0 = fmaf(fv, wr[0], y0); y1 = fmaf(fv, wr[1], y1);
      y2 = fmaf(fv, wr[2], y2); y3 = fmaf(fv, wr[3], y3);
    }
    a0 += fmaxf(fmaf(y0, s0, o0), 0.f);
    a1 += fmaxf(fmaf(y1, s1, o1), 0.f);
    a2 += fmaxf(fmaf(y2, s2, o2), 0.f);
    a3 += fmaxf(fmaf(y3, s3, o3), 0.f);
  }
  float il = 1.0f / (float)len;
  segt[(size_t)(c0+0)*segstride + r] = a0*il;
  segt[(size_t)(c0+1)*segstride + r] = a1*il;
  segt[(size_t)(c0+2)*segstride + r] = a2*il;
  segt[(size_t)(c0+3)*segstride + r] = a3*il;
}

// ------- layer 2 LDS-tiled GEMM; A computed in-kernel; fused stats ----------
template<int C1>
__global__ __launch_bounds__(BLK) void k_y2t(const float4* __restrict__ srt,
    const int* __restrict__ jrank, const float4* __restrict__ vmean,
    const float* __restrict__ W1, const float* __restrict__ coef1,
    const float* __restrict__ segt, int segstride,
    const float* __restrict__ W2, float* __restrict__ Y2,
    float* __restrict__ part,
    int gx, int gy, int gz, float vx, float vy, float vz) {
  constexpr int K  = 2*C1;
  constexpr int C2 = 2*C1;
  constexpr int MT = 64;
  constexpr int NT = 64;
  constexpr int NPAN = C2 / NT;
  __shared__ float At[K*MT];   // [k][j]; reused as reduction scratch at end
  __shared__ float Bp[K*NT];   // [k][c]; prologue aliases live here (dead by panel 0)
  float* w1A  = Bp;                            // 10*C1 floats
  float* fA   = Bp + 10*C1;                    // 64*11 floats (stride 11: bank spread)
  int*   jrlA = (int*)(Bp + 10*C1 + MT*11);    // 64 ints
  const int tid  = threadIdx.x;
  const int base = blockIdx.x * MT;

  for (int t = tid; t < 10*C1; t += BLK) w1A[t] = W1[t];
  if (tid < MT) {
    int jr = jrank[base + tid];
    jrlA[tid] = jr;
    float4 p  = srt[base + tid];
    float4 vmn = vmean[jr];
    float f[10];
    build_f(p, vmn, vx, vy, vz, gx, gy, gz, f);
    #pragma unroll
    for (int d = 0; d < 10; d++) fA[tid*11 + d] = f[d];
  }
  __syncthreads();

  // A-tile first C1 rows: y1 computed from f + W1, BN+ReLU applied.
  for (int it = tid; it < (C1/4)*MT; it += BLK) {
    int kq = it >> 6;                 // wave-uniform
    int j  = it & 63;
    int c0 = kq * 4;
    float y0=0.f, y1=0.f, y2=0.f, y3=0.f;
    #pragma unroll
    for (int d = 0; d < 10; d++) {
      float fv = fA[j*11 + d];
      const float* wr = &w1A[d*C1 + c0];
      y0 = fmaf(fv, wr[0], y0); y1 = fmaf(fv, wr[1], y1);
      y2 = fmaf(fv, wr[2], y2); y3 = fmaf(fv, wr[3], y3);
    }
    At[(c0+0)*MT + j] = fmaxf(fmaf(y0, coef1[c0+0], coef1[C1+c0+0]), 0.f);
    At[(c0+1)*MT + j] = fmaxf(fmaf(y1, coef1[c0+1], coef1[C1+c0+1]), 0.f);
    At[(c0+2)*MT + j] = fmaxf(fmaf(y2, coef1[c0+2], coef1[C1+c0+2]), 0.f);
    At[(c0+3)*MT + j] = fmaxf(fmaf(y3, coef1[c0+3], coef1[C1+c0+3]), 0.f);
  }
  // A-tile seg half (gather via jrl; consecutive-lane stores, conflict-free).
  for (int it = tid; it < C1*MT; it += BLK) {
    int c = it >> 6;
    int j = it & 63;
    At[(C1 + c)*MT + j] = segt[(size_t)c*segstride + jrlA[j]];
  }

  const int w      = tid >> 6;
  const int lane   = tid & 63;
  const int colg   = lane & 15;
  const int rowsub = lane >> 4;
  const int arow   = w*16 + rowsub*4;

  float cs[NPAN][4], cq[NPAN][4];
  #pragma unroll
  for (int p = 0; p < NPAN; p++) {
    __syncthreads();   // At+aliases done (p=0) / previous panel compute done
    for (int it = tid; it < K*(NT/4); it += BLK) {
      int k   = it >> 4;
      int cq4 = (it & 15) << 2;
      *(float4*)&Bp[k*NT + cq4] = *(const float4*)&W2[(size_t)k*C2 + p*NT + cq4];
    }
    __syncthreads();
    float4 ac0 = {0,0,0,0}, ac1 = {0,0,0,0}, ac2 = {0,0,0,0}, ac3 = {0,0,0,0};
    #pragma unroll 8
    for (int k = 0; k < K; k++) {
      float4 a = *(const float4*)&At[k*MT + arow];
      float4 b = *(const float4*)&Bp[k*NT + colg*4];
      ac0.x = fmaf(a.x, b.x, ac0.x); ac0.y = fmaf(a.x, b.y, ac0.y);
      ac0.z = fmaf(a.x, b.z, ac0.z); ac0.w = fmaf(a.x, b.w, ac0.w);
      ac1.x = fmaf(a.y, b.x, ac1.x); ac1.y = fmaf(a.y, b.y, ac1.y);
      ac1.z = fmaf(a.y, b.z, ac1.z); ac1.w = fmaf(a.y, b.w, ac1.w);
      ac2.x = fmaf(a.z, b.x, ac2.x); ac2.y = fmaf(a.z, b.y, ac2.y);
      ac2.z = fmaf(a.z, b.z, ac2.z); ac2.w = fmaf(a.z, b.w, ac2.w);
      ac3.x = fmaf(a.w, b.x, ac3.x); ac3.y = fmaf(a.w, b.y, ac3.y);
      ac3.z = fmaf(a.w, b.z, ac3.z); ac3.w = fmaf(a.w, b.w, ac3.w);
    }
    cs[p][0] = ac0.x + ac1.x + ac2.x + ac3.x;
    cs[p][1] = ac0.y + ac1.y + ac2.y + ac3.y;
    cs[p][2] = ac0.z + ac1.z + ac2.z + ac3.z;
    cs[p][3] = ac0.w + ac1.w + ac2.w + ac3.w;
    cq[p][0] = ac0.x*ac0.x + ac1.x*ac1.x + ac2.x*ac2.x + ac3.x*ac3.x;
    cq[p][1] = ac0.y*ac0.y + ac1.y*ac1.y + ac2.y*ac2.y + ac3.y*ac3.y;
    cq[p][2] = ac0.z*ac0.z + ac1.z*ac1.z + ac2.z*ac2.z + ac3.z*ac3.z;
    cq[p][3] = ac0.w*ac0.w + ac1.w*ac1.w + ac2.w*ac2.w + ac3.w*ac3.w;
    size_t ob = (size_t)(base + arow)*C2 + p*NT + colg*4;
    *(float4*)&Y2[ob + 0*C2] = ac0;
    *(float4*)&Y2[ob + 1*C2] = ac1;
    *(float4*)&Y2[ob + 2*C2] = ac2;
    *(float4*)&Y2[ob + 3*C2] = ac3;
  }

  // ---- fused per-block column sum/sumsq partials (reuse At as scratch) ----
  __syncthreads();
  float* red = At;                 // [32][C2+1]
  const int contrib = w*4 + rowsub;
  #pragma unroll
  for (int p = 0; p < NPAN; p++) {
    #pragma unroll
    for (int e = 0; e < 4; e++) {
      red[contrib*(C2+1) + p*NT + colg*4 + e]        = cs[p][e];
      red[(16 + contrib)*(C2+1) + p*NT + colg*4 + e] = cq[p][e];
    }
  }
  __syncthreads();
  if (tid < C2) {
    float s = 0.f, q = 0.f;
    #pragma unroll 4
    for (int i = 0; i < 16; i++) {
      s += red[i*(C2+1) + tid];
      q += red[(16 + i)*(C2+1) + tid];
    }
    part[(size_t)blockIdx.x*2*C2 + tid]      = s;
    part[(size_t)blockIdx.x*2*C2 + C2 + tid] = q;
  }
}

// -------- layer-2 BN+ReLU + voxel mean (row-major Y2, out row stride C) -----
template<int C>
__global__ __launch_bounds__(BLK) void k_hseg2(const float* __restrict__ Y,
    const float* __restrict__ coef, const int* __restrict__ uniq,
    const int* __restrict__ cnt, const int* __restrict__ woff,
    const int* __restrict__ Up, float* __restrict__ outm) {
  __shared__ float sc[C], sb[C];
  for (int t = threadIdx.x; t < C; t += BLK) { sc[t] = coef[t]; sb[t] = coef[C + t]; }
  __syncthreads();
  constexpr int QPB = C/4;
  int tid = blockIdx.x * BLK + threadIdx.x;
  int r = tid / QPB;
  int q = tid % QPB;
  if (r >= *Up) return;
  int lin = uniq[r];
  int len = cnt[lin];
  int base = woff[r] - len;
  int c0 = q * 4;
  float s0 = sc[c0+0], s1 = sc[c0+1], s2 = sc[c0+2], s3 = sc[c0+3];
  float o0 = sb[c0+0], o1 = sb[c0+1], o2 = sb[c0+2], o3 = sb[c0+3];
  float a0=0.f, a1=0.f, a2=0.f, a3=0.f;
  for (int k = 0; k < len; k++) {
    float4 v = *(const float4*)&Y[(size_t)(base + k)*C + c0];
    a0 += fmaxf(fmaf(v.x, s0, o0), 0.f);
    a1 += fmaxf(fmaf(v.y, s1, o1), 0.f);
    a2 += fmaxf(fmaf(v.z, s2, o2), 0.f);
    a3 += fmaxf(fmaf(v.w, s3, o3), 0.f);
  }
  float il = 1.0f / (float)len;
  float4 o = {a0*il, a1*il, a2*il, a3*il};
  *(float4*)&outm[(size_t)r*C + c0] = o;
}

// ---------------- top-scale tail zero + coors ----------------
__global__ __launch_bounds__(BLK) void k_fin2(const int* __restrict__ uniq,
    const int* __restrict__ Up, float* __restrict__ vf, float* __restrict__ coors) {
  int idx = blockIdx.x * BLK + threadIdx.x;
  int r = idx >> 5;
  int cc = (idx & 31) << 2;
  if (r >= NPTS) return;
  int U = *Up;
  if (r >= U) {
    float4 z = {0.f, 0.f, 0.f, 0.f};
    *(float4*)&vf[(size_t)r*128 + cc] = z;
  }
  if (cc == 0) {
    float4 co;
    if (r < U) {
      int lin = uniq[r];
      int x = lin % TGX; int t = lin / TGX;
      int y = t % TGY;   t /= TGY;
      int z = t % TGZ;   int b = t / TGZ;
      co.x = (float)b; co.y = (float)z; co.z = (float)y; co.w = (float)x;
    } else {
      co.x = -1.f; co.y = -1.f; co.z = -1.f; co.w = -1.f;
    }
    *(float4*)&coors[(size_t)r*4] = co;
  }
}

// ------------- merge: per-parent child-rank list (gather) -------------------
__global__ __launch_bounds__(BLK) void k_clist(const int* __restrict__ tuniq,
    const int* __restrict__ Utp, const int* __restrict__ scnt,
    const int* __restrict__ srank, int* __restrict__ clist, int* __restrict__ mcnt,
    int gx, int gy, int gz, int f) {
  int r = blockIdx.x * BLK + threadIdx.x;
  if (r >= *Utp) return;
  int lin = tuniq[r];
  int x = lin % TGX; int t = lin / TGX;
  int y = t % TGY;   int b = t / TGY;   // TGZ == 1 so z == 0
  int m = 0;
  for (int cz = 0; cz < gz; cz++)
    for (int yy = y*f; yy < y*f + f; yy++)
      for (int xx = x*f; xx < x*f + f; xx++) {
        int cl = ((b*gz + cz)*gy + yy)*gx + xx;
        if (scnt[cl] > 0) clist[(size_t)r*64 + (m++)] = srank[cl];
      }
  mcnt[r] = m;
}

__global__ __launch_bounds__(BLK) void k_merge2(const float* __restrict__ voxfeat,
    const int* __restrict__ clist, const int* __restrict__ mcnt,
    const int* __restrict__ Utp, float* __restrict__ dest) {
  int idx = blockIdx.x * BLK + threadIdx.x;
  int r = idx >> 4;
  int q = idx & 15;
  if (r >= *Utp) return;
  int m = mcnt[r];
  float a0=0.f, a1=0.f, a2=0.f, a3=0.f;
  for (int t = 0; t < m; t++) {
    int cr = clist[(size_t)r*64 + t];
    float4 v = *(const float4*)&voxfeat[(size_t)cr*64 + q*4];
    a0 += v.x; a1 += v.y; a2 += v.z; a3 += v.w;
  }
  float inv = 1.0f / (float)max(m, 1);
  float4 o = {a0*inv, a1*inv, a2*inv, a3*inv};
  *(float4*)&dest[(size_t)r*64 + q*4] = o;
}

// ---------------- merged output compose (valid rows + zero tail) ------------
__global__ __launch_bounds__(BLK) void k_finmg(const float* __restrict__ maccm,
    const float* __restrict__ maccl, const int* __restrict__ Up,
    float* __restrict__ out) {
  int idx = blockIdx.x * BLK + threadIdx.x;
  int r = idx >> 5;
  int q = idx & 31;
  if (r >= NPTS) return;
  float4 v = {0.f, 0.f, 0.f, 0.f};
  if (r < *Up)
    v = (q < 16) ? *(const float4*)&maccm[(size_t)r*64 + q*4]
                 : *(const float4*)&maccl[(size_t)r*64 + (q-16)*4];
  *(float4*)&out[(size_t)r*128 + q*4] = v;
}

// ---------------- one VFE scale (post-sort part) ----------------
template<int C1>
static void run_vfe(hipStream_t stream,
    int gx, int gy, int gz, float vx, float vy, float vz, int UB, int segstride,
    const float* W1, const float* g1, const float* b1,
    const float* W2, const float* g2, const float* b2,
    const int* cntg, const int* uniq, const int* woff, const int* U,
    const float4* srt, const int* jrank, const float4* vmean,
    float* segt, float* part, float* coef1, float* coef2,
    float* Y2, float* hout) {
  constexpr int C2 = 2 * C1;
  k_stats1<C1><<<ST1BLKS, BLK, 0, stream>>>(srt, jrank, vmean, W1, part,
      gx, gy, gz, vx, vy, vz);
  k_partcoef<C1><<<C1, BLK, 0, stream>>>(part, ST1BLKS, g1, b1, coef1);
  k_hsegT<C1><<<((size_t)UB*(C1/4) + BLK - 1)/BLK, BLK, 0, stream>>>(
      srt, vmean, W1, coef1, uniq, cntg, woff, U, segt, segstride,
      gx, gy, gz, vx, vy, vz);
  k_y2t<C1><<<Y2BLKS, BLK, 0, stream>>>(srt, jrank, vmean, W1, coef1,
      segt, segstride, W2, Y2, part, gx, gy, gz, vx, vy, vz);
  k_partcoef<C2><<<C2, BLK, 0, stream>>>(part, Y2BLKS, g2, b2, coef2);
  k_hseg2<C2><<<((size_t)UB*(C2/4) + BLK - 1)/BLK, BLK, 0, stream>>>(
      Y2, coef2, uniq, cntg, woff, U, hout);
}

extern "C" void kernel_launch(void* const* d_in, const int* in_sizes, int n_in,
                              void* d_out, int out_size, void* d_ws, size_t ws_size,
                              hipStream_t stream) {
  const float* pts = (const float*)d_in[0];
  const float* W1t = (const float*)d_in[2];
  const float* g1t = (const float*)d_in[3];
  const float* b1t = (const float*)d_in[4];
  const float* W2t = (const float*)d_in[5];
  const float* g2t = (const float*)d_in[6];
  const float* b2t = (const float*)d_in[7];
  const float* W1m = (const float*)d_in[8];
  const float* g1m = (const float*)d_in[9];
  const float* b1m = (const float*)d_in[10];
  const float* W2m = (const float*)d_in[11];
  const float* g2m = (const float*)d_in[12];
  const float* b2m = (const float*)d_in[13];
  const float* W1l = (const float*)d_in[14];
  const float* g1l = (const float*)d_in[15];
  const float* b1l = (const float*)d_in[16];
  const float* W2l = (const float*)d_in[17];
  const float* g2l = (const float*)d_in[18];
  const float* b2l = (const float*)d_in[19];

  float* out = (float*)d_out;
  float* vf = out;                              // N x 128 (final vf)
  float* mg = out + (size_t)NPTS * 128;         // N x 128 (Y2 scratch, then merged)
  float* co = out + (size_t)NPTS * 256;         // N x 4   (coors)

  char* w = (char*)d_ws;
  size_t off = 0;
  auto alloc = [&](size_t bytes) -> void* {
    void* p = w + off;
    off = (off + bytes + 1023) & ~(size_t)1023;
    return p;
  };
  int*    cnt_t  = (int*)alloc(((size_t)G_TOPC + G_MEDC + G_LOWC) * 4); // contiguous
  int*    cnt_m  = cnt_t + G_TOPC;
  int*    cnt_l  = cnt_t + G_TOPC + G_MEDC;
  int*    rank_t = (int*)alloc((size_t)G_TOPC * 4);
  int*    rank_m = (int*)alloc((size_t)G_MEDC * 4);
  int*    rank_l = (int*)alloc((size_t)G_LOWC * 4);
  int*    uniq_t = (int*)alloc((size_t)G_TOPC * 4);
  int*    uniq_m = (int*)alloc((size_t)NPTS * 4);
  int*    uniq_l = (int*)alloc((size_t)NPTS * 4);
  int*    woff_t = (int*)alloc((size_t)G_TOPC * 4);
  int*    woff_m = (int*)alloc((size_t)NPTS * 4);
  int*    woff_l = (int*)alloc((size_t)NPTS * 4);
  float4* srt_t  = (float4*)alloc((size_t)NPTS * 16);
  float4* srt_m  = (float4*)alloc((size_t)NPTS * 16);
  float4* srt_l  = (float4*)alloc((size_t)NPTS * 16);
  int*    jr_t   = (int*)alloc((size_t)NPTS * 4);
  int*    jr_m   = (int*)alloc((size_t)NPTS * 4);
  int*    jr_l   = (int*)alloc((size_t)NPTS * 4);
  float4* vm_t   = (float4*)alloc((size_t)G_TOPC * 16);
  float4* vm_m   = (float4*)alloc((size_t)NPTS * 16);
  float4* vm_l   = (float4*)alloc((size_t)NPTS * 16);
  float*  segt   = (float*)alloc((size_t)NPTS * 32 * 4);   // also clist alias
  float*  voxfeat= (float*)alloc((size_t)NPTS * 64 * 4);   // med/low hseg2 out
  int*    mcnt   = (int*)alloc((size_t)G_TOPC * 4);
  float*  maccm  = (float*)alloc((size_t)G_TOPC * 64 * 4);
  float*  maccl  = (float*)alloc((size_t)G_TOPC * 64 * 4);
  float*  part   = (float*)alloc((size_t)Y2BLKS * 256 * 4);
  float*  coef1  = (float*)alloc(2 * 128 * 4);
  float*  coef2  = (float*)alloc(2 * 128 * 4);
  int2*   bsum   = (int2*)alloc(1024 * 8);
  int*    Ut     = (int*)alloc(64);
  int*    Um     = (int*)alloc(64);
  int*    Ul     = (int*)alloc(64);
  (void)in_sizes; (void)n_in; (void)out_size; (void)ws_size;

  int* clist = (int*)segt;   // alias: segt dead between y2t and next hsegT

  // ---- batched voxelization front-end (all 3 scales) ----
  (void)hipMemsetAsync(cnt_t, 0, ((size_t)G_TOPC + G_MEDC + G_LOWC) * 4, stream);
  k_count3<<<NPTS/BLK, BLK, 0, stream>>>(pts, cnt_t, cnt_m, cnt_l);
  k_scan1_all<<<NB_T + NB_M + NB_L, BLK, 0, stream>>>(cnt_t, cnt_m, cnt_l, bsum);
  k_scan2_all<<<1, 1024, 0, stream>>>(bsum, Ut, Um, Ul);
  k_scan3_all<<<NB_T + NB_M + NB_L, BLK, 0, stream>>>(cnt_t, cnt_m, cnt_l, bsum,
      rank_t, rank_m, rank_l, uniq_t, uniq_m, uniq_l, woff_t, woff_m, woff_l);
  k_scatter3<<<NPTS/BLK, BLK, 0, stream>>>(pts,
      rank_t, woff_t, srt_t, jr_t,
      rank_m, woff_m, srt_m, jr_m,
      rank_l, woff_l, srt_l, jr_l);
  k_vox13<<<NBVT + NBVM + NBVL, BLK, 0, stream>>>(
      srt_t, uniq_t, cnt_t, woff_t, Ut, vm_t,
      srt_m, uniq_m, cnt_m, woff_m, Um, vm_m,
      srt_l, uniq_l, cnt_l, woff_l, Ul, vm_l);

  // ---- TOP scale (C1=64, C2=128): Y2 in mg (full), voxel means -> vf rows.
  run_vfe<64>(stream, 176, 200, 1, 0.4f, 0.4f, 4.0f, G_TOPC, G_TOPC,
              W1t, g1t, b1t, W2t, g2t, b2t,
              cnt_t, uniq_t, woff_t, Ut, srt_t, jr_t, vm_t,
              segt, part, coef1, coef2, /*Y2*/ mg, /*hout*/ vf);
  k_fin2<<<(NPTS*32)/BLK, BLK, 0, stream>>>(uniq_t, Ut, vf, co);

  // ---- MED scale (C1=32, C2=64): Y2 in mg[0,64N), means -> voxfeat.
  run_vfe<32>(stream, 352, 400, 2, 0.2f, 0.2f, 2.0f, NPTS, NPTS,
              W1m, g1m, b1m, W2m, g2m, b2m,
              cnt_m, uniq_m, woff_m, Um, srt_m, jr_m, vm_m,
              segt, part, coef1, coef2, /*Y2*/ mg, /*hout*/ voxfeat);
  k_clist<<<(G_TOPC + BLK - 1)/BLK, BLK, 0, stream>>>(uniq_t, Ut, cnt_m, rank_m,
      clist, mcnt, 352, 400, 2, 2);
  k_merge2<<<((size_t)G_TOPC*16 + BLK - 1)/BLK, BLK, 0, stream>>>(voxfeat, clist,
      mcnt, Ut, maccm);

  // ---- LOW scale (C1=32, C2=64): Y2 in mg[64N,128N), means -> voxfeat.
  run_vfe<32>(stream, 704, 800, 4, 0.1f, 0.1f, 1.0f, NPTS, NPTS,
              W1l, g1l, b1l, W2l, g2l, b2l,
              cnt_l, uniq_l, woff_l, Ul, srt_l, jr_l, vm_l,
              segt, part, coef1, coef2, /*Y2*/ mg + (size_t)NPTS*64, /*hout*/ voxfeat);
  k_clist<<<(G_TOPC + BLK - 1)/BLK, BLK, 0, stream>>>(uniq_t, Ut, cnt_l, rank_l,
      clist, mcnt, 704, 800, 4, 4);
  k_merge2<<<((size_t)G_TOPC*16 + BLK - 1)/BLK, BLK, 0, stream>>>(voxfeat, clist,
      mcnt, Ut, maccl);

  // ---- final merged output (valid rows from macc, tail zero).
  k_finmg<<<(NPTS*32)/BLK, BLK, 0, stream>>>(maccm, maccl, Ut, mg);
}